// Round 4
// baseline (647.350 us; speedup 1.0000x reference)
//
#include <hip/hip_runtime.h>
#include <hip/hip_bf16.h>

// Problem constants
#define B_SZ  64
#define CIN   512
#define T_IN  2048
#define COUT  512
#define KW_   5
#define TOUT  2044

// Main kernel (round 4): 256 threads (4 waves), tile 128(co) x 512(t), BK=32.
// Each wave owns 128(co) x 128(t): acc[8][8] = 256 AGPR.
// __launch_bounds__(256,1) -> 1 wave/SIMD -> 512 unified regs/wave:
//   256 AGPR + ~180 arch VGPR fits with headroom (rounds 2-3 spilled because
//   8-wave geometry gave only 256 total for acc=128 + pipeline state).
// reads/MFMA = 16 ds_read_b128 per kw for 64 MFMA = 0.25 (<0.40 LDS-keeps-up
// threshold: 12cyc/read vs 4.85cyc/MFMA per CU) -- LDS no longer co-limits
// (128x64 wave tile was 0.375 = 93% LDS busy at MFMA rate).
// Double-buffered LDS + counted vmcnt (T3+T4):
//   stage(buf0); loop { stage(buf^1,next); s_waitcnt vmcnt(18); s_barrier;
//   compute(buf); s_barrier; }
// Per wave per stage: 10 W + 8 X loads = 18 (+1 exec-masked X-tail on wave 0;
// FIFO vmcnt makes vmcnt(18) conservative there). No vmcnt(0) in steady state.
// LDS bank-conflict XOR swizzle (chunk ^= (row>>1)&3) on BOTH the
// global_load_lds SOURCE and the ds_read address (rule #21); verified
// SQ_LDS_BANK_CONFLICT == 0.
#define BM    128
#define BN    512
#define BK    32
#define XROWS 516   // 512 t + 4 halo rows (kw window)

typedef __attribute__((ext_vector_type(8))) short   short8;
typedef __attribute__((ext_vector_type(4))) float   floatx4;

__device__ __forceinline__ unsigned short f2bf(float f) {
    unsigned int u = __builtin_bit_cast(unsigned int, f);
    u += 0x7fffu + ((u >> 16) & 1u);   // RNE
    return (unsigned short)(u >> 16);
}

__device__ __forceinline__ void gl_lds16(const void* g, void* l) {
    __builtin_amdgcn_global_load_lds(
        (const __attribute__((address_space(1))) unsigned int*)g,
        (__attribute__((address_space(3))) unsigned int*)l, 16, 0, 0);
}

// ---------------- pre-kernel 1: W fp32 [co][ci][kw] -> bf16 [kw][co][ci] ----
__global__ __launch_bounds__(256)
void wconv_kernel(const float* __restrict__ w, unsigned short* __restrict__ wbf) {
    int i = blockIdx.x * 256 + threadIdx.x;
    if (i < COUT * CIN * KW_) {
        int kw = i % KW_;
        int r  = i / KW_;
        int ci = r % CIN;
        int co = r / CIN;
        wbf[((size_t)kw * COUT + co) * CIN + ci] = f2bf(w[i]);
    }
}

// ---------------- pre-kernel 2: X fp32 [b][ci][t] -> bf16 [b][t][ci] --------
__global__ __launch_bounds__(256)
void xtrans_kernel(const float* __restrict__ x, unsigned short* __restrict__ xbf) {
    __shared__ float tile[64][68];
    const int t0  = blockIdx.x * 64;
    const int ci0 = blockIdx.y * 64;
    const int b   = blockIdx.z;
    const int tid = threadIdx.x;

    const float* xb = x + ((size_t)b * CIN + ci0) * T_IN + t0;
    const int cl = tid >> 4, fc = tid & 15;
#pragma unroll
    for (int p = 0; p < 4; ++p) {
        float4 v = *reinterpret_cast<const float4*>(xb + (size_t)(cl + p * 16) * T_IN + fc * 4);
        *reinterpret_cast<float4*>(&tile[cl + p * 16][fc * 4]) = v;
    }
    __syncthreads();

    const int tl = tid >> 2, cg = (tid & 3) * 16;
    unsigned short tmp[16];
#pragma unroll
    for (int j = 0; j < 16; ++j) tmp[j] = f2bf(tile[cg + j][tl]);
    unsigned short* dst = xbf + ((size_t)b * T_IN + t0 + tl) * CIN + ci0 + cg;
    *reinterpret_cast<short8*>(dst)     = *reinterpret_cast<short8*>(tmp);
    *reinterpret_cast<short8*>(dst + 8) = *reinterpret_cast<short8*>(tmp + 8);
}

// ---- main kernel: 128x512 block, 4 waves of 128x128, dbuf + counted vmcnt --
__global__ __launch_bounds__(256, 1)
void tdl_conv_mega(const unsigned short* __restrict__ xbf,
                   const unsigned short* __restrict__ wbf,
                   const float* __restrict__ bias,
                   float* __restrict__ out)
{
    // Wl: 2 x [5][128][32] bf16 = 81920 B ; Xl: 2 x [516][32] bf16 = 66048 B
    // total 147968 B <= 160 KiB -> 1 block/CU (4 waves, 1/SIMD)
    __shared__ __align__(16) unsigned short Wl[2][KW_ * BM * BK];
    __shared__ __align__(16) unsigned short Xl[2][XROWS * BK];

    const int tid  = threadIdx.x;
    const int lane = tid & 63;
    const int wv   = tid >> 6;   // 0..3: t sub-range owner (128 t each)

    // XCD-aware swizzle (grid 1024 % 8 == 0 -> bijective); co fastest so the
    // 8 blocks sharing an X tile land near each other in XCD-chunk order.
    const int bid     = blockIdx.x;
    const int logical = ((bid & 7) << 7) | (bid >> 3);
    const int co_t = logical & 3;
    const int t_t  = (logical >> 2) & 3;
    const int b    = logical >> 4;

    const int co0 = co_t * BM;
    const int t0  = t_t * BN;

    const unsigned short* xb = xbf + (size_t)b * T_IN * CIN;

    floatx4 acc[8][8];
#pragma unroll
    for (int m = 0; m < 8; ++m)
#pragma unroll
        for (int n = 0; n < 8; ++n)
            acc[m][n] = (floatx4)(0.0f);

    const int arow = lane & 15;
    const int c0   = lane >> 4;                       // logical 16B chunk
    const int aswz = ((c0 ^ ((arow >> 1) & 3)) << 3); // W read swizzle (elems)

    // ---- staging: W 2560 chunks (10/thread), X 2064 (8/thread + 16 tail) ---
    auto stage = [&](int sel, int ci0) {
#pragma unroll
        for (int it = 0; it < 10; ++it) {
            const int e  = tid + it * 256;
            const int kw = e >> 9;
            const int r  = e & 511;
            const int co = r >> 2;
            const int c8 = (((r & 3) ^ ((co >> 1) & 3)) << 3);
            gl_lds16(wbf + ((size_t)(kw * COUT + co0 + co)) * CIN + ci0 + c8,
                     &Wl[sel][e * 8]);
        }
#pragma unroll
        for (int it = 0; it < 8; ++it) {
            const int e  = tid + it * 256;
            const int t  = e >> 2;
            const int c8 = (((e & 3) ^ ((t >> 1) & 3)) << 3);
            gl_lds16(xb + (size_t)(t0 + t) * CIN + ci0 + c8, &Xl[sel][e * 8]);
        }
        if (tid < 16) {
            const int e  = 2048 + tid;
            const int t  = e >> 2;   // 512..515
            const int c8 = (((e & 3) ^ ((t >> 1) & 3)) << 3);
            int ts = t0 + t; if (ts > T_IN - 1) ts = T_IN - 1;  // feeds masked cols only
            gl_lds16(xb + (size_t)ts * CIN + ci0 + c8, &Xl[sel][e * 8]);
        }
    };

    // compute: per kw read af[8] + bfr[8] (16 ds_read_b128) then 64 MFMAs.
    auto compute = [&](int sel) {
#pragma unroll
        for (int kw = 0; kw < KW_; ++kw) {
            // X swizzle: row = wv*128+n*16+arow+kw -> (row>>1)&3 = ((arow+kw)>>1)&3
            const int bswz = ((c0 ^ (((arow + kw) >> 1) & 3)) << 3);
            short8 af[8], bfr[8];
#pragma unroll
            for (int m = 0; m < 8; ++m)
                af[m] = *reinterpret_cast<const short8*>(
                    &Wl[sel][(kw * BM + m * 16 + arow) * BK + aswz]);
#pragma unroll
            for (int n = 0; n < 8; ++n)
                bfr[n] = *reinterpret_cast<const short8*>(
                    &Xl[sel][(wv * 128 + n * 16 + arow + kw) * BK + bswz]);
            __builtin_amdgcn_s_setprio(1);
#pragma unroll
            for (int m = 0; m < 8; ++m)
#pragma unroll
                for (int n = 0; n < 8; ++n)
                    acc[m][n] = __builtin_amdgcn_mfma_f32_16x16x32_bf16(
                        af[m], bfr[n], acc[m][n], 0, 0, 0);
            __builtin_amdgcn_s_setprio(0);
        }
    };

    // ---- pipelined K-loop: 16 ci-tiles, 2x unrolled for static buffer sel ----
    stage(0, 0);
#pragma unroll 1
    for (int i = 0; i < 16; i += 2) {
        // even half: prefetch tile i+1 into buf1, compute tile i from buf0
        stage(1, (i + 1) * BK);
        asm volatile("s_waitcnt vmcnt(18)" ::: "memory");  // tile-i loads landed
        __builtin_amdgcn_sched_barrier(0);
        __builtin_amdgcn_s_barrier();
        __builtin_amdgcn_sched_barrier(0);
        compute(0);
        __builtin_amdgcn_s_barrier();                      // buf0 reads done
        __builtin_amdgcn_sched_barrier(0);

        // odd half: prefetch tile i+2 into buf0, compute tile i+1 from buf1
        if (i + 2 < 16) {
            stage(0, (i + 2) * BK);
            asm volatile("s_waitcnt vmcnt(18)" ::: "memory");
        } else {
            asm volatile("s_waitcnt vmcnt(0)" ::: "memory");
        }
        __builtin_amdgcn_sched_barrier(0);
        __builtin_amdgcn_s_barrier();
        __builtin_amdgcn_sched_barrier(0);
        compute(1);
        __builtin_amdgcn_s_barrier();                      // buf1 reads done
        __builtin_amdgcn_sched_barrier(0);
    }

    // ---- epilogue: D layout col = lane&15 (t), row = (lane>>4)*4 + r (co)
    const int colb = wv * 128 + (lane & 15);
    const int rowb = (lane >> 4) * 4;
    float* outp = out + ((size_t)b * COUT + co0) * TOUT + t0;
#pragma unroll
    for (int m = 0; m < 8; ++m) {
        const int row0 = rowb + m * 16;
        float bv[4];
#pragma unroll
        for (int r = 0; r < 4; ++r) bv[r] = bias[co0 + row0 + r];
#pragma unroll
        for (int n = 0; n < 8; ++n) {
            const int col = colb + n * 16;
            if (t0 + col < TOUT) {
#pragma unroll
                for (int r = 0; r < 4; ++r)
                    outp[(size_t)(row0 + r) * TOUT + col] = acc[m][n][r] + bv[r];
            }
        }
    }
}

// ---------------- fallback (round-1 kernel, used if ws too small) -----------
#define PAD   40
__global__ __launch_bounds__(256, 2)
void tdl_conv_mfma(const float* __restrict__ x,
                   const float* __restrict__ w,
                   const float* __restrict__ bias,
                   float* __restrict__ out)
{
    __shared__ __align__(16) unsigned short Wlds[KW_][BM][PAD];
    __shared__ __align__(16) unsigned short Xlds[BM + 4][PAD];

    const int tid  = threadIdx.x;
    const int lane = tid & 63;
    const int wid  = tid >> 6;
    const int wm   = wid >> 1;
    const int wn   = wid & 1;

    const int bid  = blockIdx.x;
    const int co_t = bid & 3;
    const int t_t  = (bid >> 2) & 15;
    const int b    = bid >> 6;

    const int co0 = co_t * BM;
    const int t0  = t_t * BM;

    floatx4 acc[4][4];
#pragma unroll
    for (int m = 0; m < 4; ++m)
#pragma unroll
        for (int n = 0; n < 4; ++n)
            acc[m][n] = (floatx4)(0.0f);

    const float* xb = x + (size_t)b * CIN * T_IN;
    const int arow = lane & 15;
    const int k8   = (lane >> 4) * 8;

    for (int ci0 = 0; ci0 < CIN; ci0 += BK) {
        for (int e = tid; e < BK * 33; e += 256) {
            const int ci = e / 33;
            const int q  = e - ci * 33;
            const int tt = q * 4;
            const int tg = t0 + tt;
            float4 v = make_float4(0.f, 0.f, 0.f, 0.f);
            if (tg < T_IN)
                v = *reinterpret_cast<const float4*>(xb + (size_t)(ci0 + ci) * T_IN + tg);
            Xlds[tt + 0][ci] = f2bf(v.x);
            Xlds[tt + 1][ci] = f2bf(v.y);
            Xlds[tt + 2][ci] = f2bf(v.z);
            Xlds[tt + 3][ci] = f2bf(v.w);
        }
        for (int e = tid; e < BM * 40; e += 256) {
            const int co = e / 40;
            const int q  = e - co * 40;
            const float4 v = *reinterpret_cast<const float4*>(
                w + (size_t)(co0 + co) * (CIN * KW_) + ci0 * KW_ + q * 4);
            const int m0 = q * 4;
            Wlds[(m0    ) % 5][co][(m0    ) / 5] = f2bf(v.x);
            Wlds[(m0 + 1) % 5][co][(m0 + 1) / 5] = f2bf(v.y);
            Wlds[(m0 + 2) % 5][co][(m0 + 2) / 5] = f2bf(v.z);
            Wlds[(m0 + 3) % 5][co][(m0 + 3) / 5] = f2bf(v.w);
        }
        __syncthreads();
#pragma unroll
        for (int kw = 0; kw < KW_; ++kw) {
            short8 afrag[4], bfrag[4];
#pragma unroll
            for (int m = 0; m < 4; ++m)
                afrag[m] = *reinterpret_cast<const short8*>(
                    &Wlds[kw][wm * 64 + m * 16 + arow][k8]);
#pragma unroll
            for (int n = 0; n < 4; ++n)
                bfrag[n] = *reinterpret_cast<const short8*>(
                    &Xlds[wn * 64 + n * 16 + arow + kw][k8]);
#pragma unroll
            for (int m = 0; m < 4; ++m)
#pragma unroll
                for (int n = 0; n < 4; ++n)
                    acc[m][n] = __builtin_amdgcn_mfma_f32_16x16x32_bf16(
                        afrag[m], bfrag[n], acc[m][n], 0, 0, 0);
        }
        __syncthreads();
    }

    const int colb = wn * 64 + (lane & 15);
    const int rowb = wm * 64 + (lane >> 4) * 4;
    float* outp = out + ((size_t)b * COUT + co0) * TOUT + t0;
#pragma unroll
    for (int m = 0; m < 4; ++m) {
        const int row0 = rowb + m * 16;
        float bv[4];
#pragma unroll
        for (int r = 0; r < 4; ++r) bv[r] = bias[co0 + row0 + r];
#pragma unroll
        for (int n = 0; n < 4; ++n) {
            const int col = colb + n * 16;
            if (t0 + col < TOUT) {
#pragma unroll
                for (int r = 0; r < 4; ++r)
                    outp[(size_t)(row0 + r) * TOUT + col] = acc[m][n][r] + bv[r];
            }
        }
    }
}

extern "C" void kernel_launch(void* const* d_in, const int* in_sizes, int n_in,
                              void* d_out, int out_size, void* d_ws, size_t ws_size,
                              hipStream_t stream) {
    const float* x    = (const float*)d_in[0];
    const float* w    = (const float*)d_in[1];
    const float* bias = (const float*)d_in[2];
    float* out        = (float*)d_out;

    const size_t xbf_elems = (size_t)B_SZ * T_IN * CIN;
    const size_t wbf_elems = (size_t)KW_ * COUT * CIN;
    const size_t need = (xbf_elems + wbf_elems) * sizeof(unsigned short);

    if (ws_size >= need) {
        unsigned short* xbf = (unsigned short*)d_ws;
        unsigned short* wbf = xbf + xbf_elems;

        wconv_kernel<<<(COUT * CIN * KW_ + 255) / 256, 256, 0, stream>>>(w, wbf);
        dim3 tg(T_IN / 64, CIN / 64, B_SZ);
        xtrans_kernel<<<tg, 256, 0, stream>>>(x, xbf);
        // grid: 4 co-tiles * 4 t-tiles * 64 batches = 1024 blocks, 1/CU
        tdl_conv_mega<<<4 * 4 * B_SZ, 256, 0, stream>>>(xbf, wbf, bias, out);
    } else {
        tdl_conv_mfma<<<4 * 16 * B_SZ, 256, 0, stream>>>(x, w, bias, out);
    }
}

// Round 5
// 578.023 us; speedup vs baseline: 1.1199x; 1.1199x over previous
//
#include <hip/hip_runtime.h>
#include <hip/hip_bf16.h>

// Problem constants
#define B_SZ  64
#define CIN   512
#define T_IN  2048
#define COUT  512
#define KW_   5
#define TOUT  2044

// Main kernel (round 5): 256 threads (4 waves), tile 128(co) x 512(t), BK=32.
// Each wave owns 128(co) x 128(t): acc[8][8] = 256 accumulator regs.
//
// ROUND-4 POST-MORTEM: __builtin_amdgcn_mfma returns values the compiler
// allocates in ARCH VGPRs (v0-v255 encoding cap). acc=256 pinned VGPR_Count
// at 256 and spilled ~550 MB to scratch (WRITE_SIZE 816 MB). The AGPR half
// of the unified 512-reg file was unused. FIX: inline-asm MFMA with "+a"
// constraint pins acc into a0-a255; arch VGPRs (~180) hold fragments +
// addresses + kw-pipeline headroom. Deps flow through asm operands so the
// compiler still emits correct lgkmcnt before each MFMA.
//
// Per-CU model (1 block/CU, LDS forces it: 144.5 KB):
//   MFMA: 4blk x 16iter x 4w x 5kw x 64 = 81.9K mfma x 4.85cyc = 165 us floor
//   LDS reads: 4x16x(4 waves x 80KB) = 20.5 MB @ 85 B/cyc = 100 us
//   -> MFMA-bound (rounds 1-3 were co-limited: 0.375 reads/MFMA; this tile
//      is 0.25).
// Double-buffered LDS + counted vmcnt (T3+T4): per wave per stage 18 loads
// (wave0 +1 exec-masked tail; FIFO vmcnt makes vmcnt(18) conservative).
// LDS XOR swizzle (chunk ^= (row>>1)&3) on BOTH global_load_lds SOURCE and
// ds_read address (rule #21); verified SQ_LDS_BANK_CONFLICT == 0.
#define BM    128
#define BN    512
#define BK    32
#define XROWS 516   // 512 t + 4 halo rows (kw window)

typedef __attribute__((ext_vector_type(8))) short   short8;
typedef __attribute__((ext_vector_type(4))) float   floatx4;

__device__ __forceinline__ unsigned short f2bf(float f) {
    unsigned int u = __builtin_bit_cast(unsigned int, f);
    u += 0x7fffu + ((u >> 16) & 1u);   // RNE
    return (unsigned short)(u >> 16);
}

__device__ __forceinline__ void gl_lds16(const void* g, void* l) {
    __builtin_amdgcn_global_load_lds(
        (const __attribute__((address_space(1))) unsigned int*)g,
        (__attribute__((address_space(3))) unsigned int*)l, 16, 0, 0);
}

// MFMA with accumulator pinned to AGPRs (a-constraint). D=C=%0 (tied).
__device__ __forceinline__ void mfma_a(floatx4& c, short8 a, short8 b) {
    asm volatile("v_mfma_f32_16x16x32_bf16 %0, %1, %2, %0"
                 : "+a"(c) : "v"(a), "v"(b));
}

// ---------------- pre-kernel 1: W fp32 [co][ci][kw] -> bf16 [kw][co][ci] ----
__global__ __launch_bounds__(256)
void wconv_kernel(const float* __restrict__ w, unsigned short* __restrict__ wbf) {
    int i = blockIdx.x * 256 + threadIdx.x;
    if (i < COUT * CIN * KW_) {
        int kw = i % KW_;
        int r  = i / KW_;
        int ci = r % CIN;
        int co = r / CIN;
        wbf[((size_t)kw * COUT + co) * CIN + ci] = f2bf(w[i]);
    }
}

// ---------------- pre-kernel 2: X fp32 [b][ci][t] -> bf16 [b][t][ci] --------
__global__ __launch_bounds__(256)
void xtrans_kernel(const float* __restrict__ x, unsigned short* __restrict__ xbf) {
    __shared__ float tile[64][68];
    const int t0  = blockIdx.x * 64;
    const int ci0 = blockIdx.y * 64;
    const int b   = blockIdx.z;
    const int tid = threadIdx.x;

    const float* xb = x + ((size_t)b * CIN + ci0) * T_IN + t0;
    const int cl = tid >> 4, fc = tid & 15;
#pragma unroll
    for (int p = 0; p < 4; ++p) {
        float4 v = *reinterpret_cast<const float4*>(xb + (size_t)(cl + p * 16) * T_IN + fc * 4);
        *reinterpret_cast<float4*>(&tile[cl + p * 16][fc * 4]) = v;
    }
    __syncthreads();

    const int tl = tid >> 2, cg = (tid & 3) * 16;
    unsigned short tmp[16];
#pragma unroll
    for (int j = 0; j < 16; ++j) tmp[j] = f2bf(tile[cg + j][tl]);
    unsigned short* dst = xbf + ((size_t)b * T_IN + t0 + tl) * CIN + ci0 + cg;
    *reinterpret_cast<short8*>(dst)     = *reinterpret_cast<short8*>(tmp);
    *reinterpret_cast<short8*>(dst + 8) = *reinterpret_cast<short8*>(tmp + 8);
}

// ---- main kernel: 128x512 block, 4 waves of 128x128, dbuf + counted vmcnt --
__global__ __launch_bounds__(256, 1)
void tdl_conv_mega(const unsigned short* __restrict__ xbf,
                   const unsigned short* __restrict__ wbf,
                   const float* __restrict__ bias,
                   float* __restrict__ out)
{
    // Wl: 2 x [5][128][32] bf16 = 81920 B ; Xl: 2 x [516][32] bf16 = 66048 B
    // total 147968 B <= 160 KiB -> 1 block/CU (4 waves, 1/SIMD)
    __shared__ __align__(16) unsigned short Wl[2][KW_ * BM * BK];
    __shared__ __align__(16) unsigned short Xl[2][XROWS * BK];

    const int tid  = threadIdx.x;
    const int lane = tid & 63;
    const int wv   = tid >> 6;   // 0..3: t sub-range owner (128 t each)

    // XCD-aware swizzle (grid 1024 % 8 == 0 -> bijective)
    const int bid     = blockIdx.x;
    const int logical = ((bid & 7) << 7) | (bid >> 3);
    const int co_t = logical & 3;
    const int t_t  = (logical >> 2) & 3;
    const int b    = logical >> 4;

    const int co0 = co_t * BM;
    const int t0  = t_t * BN;

    const unsigned short* xb = xbf + (size_t)b * T_IN * CIN;

    floatx4 acc[8][8];
#pragma unroll
    for (int m = 0; m < 8; ++m)
#pragma unroll
        for (int n = 0; n < 8; ++n)
            acc[m][n] = (floatx4)(0.0f);

    const int arow = lane & 15;
    const int c0   = lane >> 4;                       // logical 16B chunk
    const int aswz = ((c0 ^ ((arow >> 1) & 3)) << 3); // W read swizzle (elems)

    // ---- staging: W 2560 chunks (10/thread), X 2064 (8/thread + 16 tail) ---
    auto stage = [&](int sel, int ci0) {
#pragma unroll
        for (int it = 0; it < 10; ++it) {
            const int e  = tid + it * 256;
            const int kw = e >> 9;
            const int r  = e & 511;
            const int co = r >> 2;
            const int c8 = (((r & 3) ^ ((co >> 1) & 3)) << 3);
            gl_lds16(wbf + ((size_t)(kw * COUT + co0 + co)) * CIN + ci0 + c8,
                     &Wl[sel][e * 8]);
        }
#pragma unroll
        for (int it = 0; it < 8; ++it) {
            const int e  = tid + it * 256;
            const int t  = e >> 2;
            const int c8 = (((e & 3) ^ ((t >> 1) & 3)) << 3);
            gl_lds16(xb + (size_t)(t0 + t) * CIN + ci0 + c8, &Xl[sel][e * 8]);
        }
        if (tid < 16) {
            const int e  = 2048 + tid;
            const int t  = e >> 2;   // 512..515
            const int c8 = (((e & 3) ^ ((t >> 1) & 3)) << 3);
            int ts = t0 + t; if (ts > T_IN - 1) ts = T_IN - 1;  // feeds masked cols only
            gl_lds16(xb + (size_t)ts * CIN + ci0 + c8, &Xl[sel][e * 8]);
        }
    };

    // compute: per kw read af[8] + bfr[8] (16 ds_read_b128) then 64 MFMAs.
    auto compute = [&](int sel) {
#pragma unroll
        for (int kw = 0; kw < KW_; ++kw) {
            // X swizzle: row = wv*128+n*16+arow+kw -> (row>>1)&3 = ((arow+kw)>>1)&3
            const int bswz = ((c0 ^ (((arow + kw) >> 1) & 3)) << 3);
            short8 af[8], bfr[8];
#pragma unroll
            for (int m = 0; m < 8; ++m)
                af[m] = *reinterpret_cast<const short8*>(
                    &Wl[sel][(kw * BM + m * 16 + arow) * BK + aswz]);
#pragma unroll
            for (int n = 0; n < 8; ++n)
                bfr[n] = *reinterpret_cast<const short8*>(
                    &Xl[sel][(wv * 128 + n * 16 + arow + kw) * BK + bswz]);
            __builtin_amdgcn_s_setprio(1);
#pragma unroll
            for (int m = 0; m < 8; ++m)
#pragma unroll
                for (int n = 0; n < 8; ++n)
                    mfma_a(acc[m][n], af[m], bfr[n]);
            __builtin_amdgcn_s_setprio(0);
        }
    };

    // ---- pipelined K-loop: 16 ci-tiles, 2x unrolled for static buffer sel ----
    stage(0, 0);
#pragma unroll 1
    for (int i = 0; i < 16; i += 2) {
        // even half: prefetch tile i+1 into buf1, compute tile i from buf0
        stage(1, (i + 1) * BK);
        asm volatile("s_waitcnt vmcnt(18)" ::: "memory");  // tile-i loads landed
        __builtin_amdgcn_sched_barrier(0);
        __builtin_amdgcn_s_barrier();
        __builtin_amdgcn_sched_barrier(0);
        compute(0);
        __builtin_amdgcn_s_barrier();                      // buf0 reads done
        __builtin_amdgcn_sched_barrier(0);

        // odd half: prefetch tile i+2 into buf0, compute tile i+1 from buf1
        if (i + 2 < 16) {
            stage(0, (i + 2) * BK);
            asm volatile("s_waitcnt vmcnt(18)" ::: "memory");
        } else {
            asm volatile("s_waitcnt vmcnt(0)" ::: "memory");
        }
        __builtin_amdgcn_sched_barrier(0);
        __builtin_amdgcn_s_barrier();
        __builtin_amdgcn_sched_barrier(0);
        compute(1);
        __builtin_amdgcn_s_barrier();                      // buf1 reads done
        __builtin_amdgcn_sched_barrier(0);
    }

    // ---- epilogue: D layout col = lane&15 (t), row = (lane>>4)*4 + r (co)
    const int colb = wv * 128 + (lane & 15);
    const int rowb = (lane >> 4) * 4;
    float* outp = out + ((size_t)b * COUT + co0) * TOUT + t0;
#pragma unroll
    for (int m = 0; m < 8; ++m) {
        const int row0 = rowb + m * 16;
        float bv[4];
#pragma unroll
        for (int r = 0; r < 4; ++r) bv[r] = bias[co0 + row0 + r];
#pragma unroll
        for (int n = 0; n < 8; ++n) {
            const int col = colb + n * 16;
            if (t0 + col < TOUT) {
#pragma unroll
                for (int r = 0; r < 4; ++r)
                    outp[(size_t)(row0 + r) * TOUT + col] = acc[m][n][r] + bv[r];
            }
        }
    }
}

// ---------------- fallback (round-1 kernel, used if ws too small) -----------
#define PAD   40
__global__ __launch_bounds__(256, 2)
void tdl_conv_mfma(const float* __restrict__ x,
                   const float* __restrict__ w,
                   const float* __restrict__ bias,
                   float* __restrict__ out)
{
    __shared__ __align__(16) unsigned short Wlds[KW_][BM][PAD];
    __shared__ __align__(16) unsigned short Xlds[BM + 4][PAD];

    const int tid  = threadIdx.x;
    const int lane = tid & 63;
    const int wid  = tid >> 6;
    const int wm   = wid >> 1;
    const int wn   = wid & 1;

    const int bid  = blockIdx.x;
    const int co_t = bid & 3;
    const int t_t  = (bid >> 2) & 15;
    const int b    = bid >> 6;

    const int co0 = co_t * BM;
    const int t0  = t_t * BM;

    floatx4 acc[4][4];
#pragma unroll
    for (int m = 0; m < 4; ++m)
#pragma unroll
        for (int n = 0; n < 4; ++n)
            acc[m][n] = (floatx4)(0.0f);

    const float* xb = x + (size_t)b * CIN * T_IN;
    const int arow = lane & 15;
    const int k8   = (lane >> 4) * 8;

    for (int ci0 = 0; ci0 < CIN; ci0 += BK) {
        for (int e = tid; e < BK * 33; e += 256) {
            const int ci = e / 33;
            const int q  = e - ci * 33;
            const int tt = q * 4;
            const int tg = t0 + tt;
            float4 v = make_float4(0.f, 0.f, 0.f, 0.f);
            if (tg < T_IN)
                v = *reinterpret_cast<const float4*>(xb + (size_t)(ci0 + ci) * T_IN + tg);
            Xlds[tt + 0][ci] = f2bf(v.x);
            Xlds[tt + 1][ci] = f2bf(v.y);
            Xlds[tt + 2][ci] = f2bf(v.z);
            Xlds[tt + 3][ci] = f2bf(v.w);
        }
        for (int e = tid; e < BM * 40; e += 256) {
            const int co = e / 40;
            const int q  = e - co * 40;
            const float4 v = *reinterpret_cast<const float4*>(
                w + (size_t)(co0 + co) * (CIN * KW_) + ci0 * KW_ + q * 4);
            const int m0 = q * 4;
            Wlds[(m0    ) % 5][co][(m0    ) / 5] = f2bf(v.x);
            Wlds[(m0 + 1) % 5][co][(m0 + 1) / 5] = f2bf(v.y);
            Wlds[(m0 + 2) % 5][co][(m0 + 2) / 5] = f2bf(v.z);
            Wlds[(m0 + 3) % 5][co][(m0 + 3) / 5] = f2bf(v.w);
        }
        __syncthreads();
#pragma unroll
        for (int kw = 0; kw < KW_; ++kw) {
            short8 afrag[4], bfrag[4];
#pragma unroll
            for (int m = 0; m < 4; ++m)
                afrag[m] = *reinterpret_cast<const short8*>(
                    &Wlds[kw][wm * 64 + m * 16 + arow][k8]);
#pragma unroll
            for (int n = 0; n < 4; ++n)
                bfrag[n] = *reinterpret_cast<const short8*>(
                    &Xlds[wn * 64 + n * 16 + arow + kw][k8]);
#pragma unroll
            for (int m = 0; m < 4; ++m)
#pragma unroll
                for (int n = 0; n < 4; ++n)
                    acc[m][n] = __builtin_amdgcn_mfma_f32_16x16x32_bf16(
                        afrag[m], bfrag[n], acc[m][n], 0, 0, 0);
        }
        __syncthreads();
    }

    const int colb = wn * 64 + (lane & 15);
    const int rowb = wm * 64 + (lane >> 4) * 4;
    float* outp = out + ((size_t)b * COUT + co0) * TOUT + t0;
#pragma unroll
    for (int m = 0; m < 4; ++m) {
        const int row0 = rowb + m * 16;
        float bv[4];
#pragma unroll
        for (int r = 0; r < 4; ++r) bv[r] = bias[co0 + row0 + r];
#pragma unroll
        for (int n = 0; n < 4; ++n) {
            const int col = colb + n * 16;
            if (t0 + col < TOUT) {
#pragma unroll
                for (int r = 0; r < 4; ++r)
                    outp[(size_t)(row0 + r) * TOUT + col] = acc[m][n][r] + bv[r];
            }
        }
    }
}

extern "C" void kernel_launch(void* const* d_in, const int* in_sizes, int n_in,
                              void* d_out, int out_size, void* d_ws, size_t ws_size,
                              hipStream_t stream) {
    const float* x    = (const float*)d_in[0];
    const float* w    = (const float*)d_in[1];
    const float* bias = (const float*)d_in[2];
    float* out        = (float*)d_out;

    const size_t xbf_elems = (size_t)B_SZ * T_IN * CIN;
    const size_t wbf_elems = (size_t)KW_ * COUT * CIN;
    const size_t need = (xbf_elems + wbf_elems) * sizeof(unsigned short);

    if (ws_size >= need) {
        unsigned short* xbf = (unsigned short*)d_ws;
        unsigned short* wbf = xbf + xbf_elems;

        wconv_kernel<<<(COUT * CIN * KW_ + 255) / 256, 256, 0, stream>>>(w, wbf);
        dim3 tg(T_IN / 64, CIN / 64, B_SZ);
        xtrans_kernel<<<tg, 256, 0, stream>>>(x, xbf);
        // grid: 4 co-tiles * 4 t-tiles * 64 batches = 1024 blocks, 1/CU
        tdl_conv_mega<<<4 * 4 * B_SZ, 256, 0, stream>>>(xbf, wbf, bias, out);
    } else {
        tdl_conv_mfma<<<4 * 16 * B_SZ, 256, 0, stream>>>(x, w, bias, out);
    }
}

// Round 6
// 440.886 us; speedup vs baseline: 1.4683x; 1.3110x over previous
//
#include <hip/hip_runtime.h>
#include <hip/hip_bf16.h>

// Problem constants
#define B_SZ  64
#define CIN   512
#define T_IN  2048
#define COUT  512
#define KW_   5
#define TOUT  2044

// Main kernel (round 6): round-0 compute geometry + dbuf pipeline.
// 256 threads (4 waves), tile 128(co) x 256(t), BK=32; each wave owns
// 128(co) x 64(t) = acc[8][4] = 128 accumulator regs (the size the compiler
// provably allocates in AGPRs without spill -- round 1: 116 arch VGPR + 0
// scratch).
//
// SESSION REGISTER LEDGER: acc=256 unallocatable (rounds 4/5: 550/350 MB
// scratch spill, VGPR pinned 256, AGPRs underused even with "+a" asm).
// acc=128 @ 8 waves/CU leaves only 128 arch -> dbuf state spills ~3 regs
// (round 3). FIX HERE: acc=128 @ 4 waves/CU: LDS dbuf = 2x57.6 = 115 KB
// forces 1 block/CU; __launch_bounds__(256,1) -> 512 unified regs/wave.
// Demand ~260 << 512: dbuf pipeline finally has register headroom, and the
// compiler has room to hoist kw+1's 12 ds_reads under kw's 32 MFMAs (the
// overlap that round 1's 2-phase structure could not express).
//
// Pipeline (T3+T4): stage(buf0); loop{ stage(buf^1,next); s_waitcnt
// vmcnt(14); s_barrier; compute(buf); s_barrier; }. Per-wave staging loads:
// 14 (wave0: 15 incl. exec-masked X tail; FIFO vmcnt -> vmcnt(14) is
// conservative there). vmcnt(0) only before the final tile's compute.
// LDS XOR swizzle (chunk ^= (row>>1)&3) on BOTH global_load_lds SOURCE and
// ds_read address (rule #21); verified SQ_LDS_BANK_CONFLICT == 0.
#define BM    128
#define BN2   256
#define BK    32

typedef __attribute__((ext_vector_type(8))) short   short8;
typedef __attribute__((ext_vector_type(4))) float   floatx4;

__device__ __forceinline__ unsigned short f2bf(float f) {
    unsigned int u = __builtin_bit_cast(unsigned int, f);
    u += 0x7fffu + ((u >> 16) & 1u);   // RNE
    return (unsigned short)(u >> 16);
}

__device__ __forceinline__ void gl_lds16(const void* g, void* l) {
    __builtin_amdgcn_global_load_lds(
        (const __attribute__((address_space(1))) unsigned int*)g,
        (__attribute__((address_space(3))) unsigned int*)l, 16, 0, 0);
}

// ---------------- pre-kernel 1: W fp32 [co][ci][kw] -> bf16 [kw][co][ci] ----
__global__ __launch_bounds__(256)
void wconv_kernel(const float* __restrict__ w, unsigned short* __restrict__ wbf) {
    int i = blockIdx.x * 256 + threadIdx.x;
    if (i < COUT * CIN * KW_) {
        int kw = i % KW_;
        int r  = i / KW_;
        int ci = r % CIN;
        int co = r / CIN;
        wbf[((size_t)kw * COUT + co) * CIN + ci] = f2bf(w[i]);
    }
}

// ---------------- pre-kernel 2: X fp32 [b][ci][t] -> bf16 [b][t][ci] --------
__global__ __launch_bounds__(256)
void xtrans_kernel(const float* __restrict__ x, unsigned short* __restrict__ xbf) {
    __shared__ float tile[64][68];
    const int t0  = blockIdx.x * 64;
    const int ci0 = blockIdx.y * 64;
    const int b   = blockIdx.z;
    const int tid = threadIdx.x;

    const float* xb = x + ((size_t)b * CIN + ci0) * T_IN + t0;
    const int cl = tid >> 4, fc = tid & 15;
#pragma unroll
    for (int p = 0; p < 4; ++p) {
        float4 v = *reinterpret_cast<const float4*>(xb + (size_t)(cl + p * 16) * T_IN + fc * 4);
        *reinterpret_cast<float4*>(&tile[cl + p * 16][fc * 4]) = v;
    }
    __syncthreads();

    const int tl = tid >> 2, cg = (tid & 3) * 16;
    unsigned short tmp[16];
#pragma unroll
    for (int j = 0; j < 16; ++j) tmp[j] = f2bf(tile[cg + j][tl]);
    unsigned short* dst = xbf + ((size_t)b * T_IN + t0 + tl) * CIN + ci0 + cg;
    *reinterpret_cast<short8*>(dst)     = *reinterpret_cast<short8*>(tmp);
    *reinterpret_cast<short8*>(dst + 8) = *reinterpret_cast<short8*>(tmp + 8);
}

// --- main kernel: 128x256 block, 4 waves of 128x64, dbuf + counted vmcnt ----
__global__ __launch_bounds__(256, 1)
void tdl_conv_db(const unsigned short* __restrict__ xbf,
                 const unsigned short* __restrict__ wbf,
                 const float* __restrict__ bias,
                 float* __restrict__ out)
{
    // Wl: 2 x [5][128][32] bf16 = 81920 B ; Xl: 2 x [260][32] bf16 = 33280 B
    // total 115200 B -> 1 block/CU (4 waves, 1/SIMD, 512 regs/wave)
    __shared__ __align__(16) unsigned short Wl[2][KW_ * BM * BK];
    __shared__ __align__(16) unsigned short Xl[2][(BN2 + 4) * BK];

    const int tid  = threadIdx.x;
    const int lane = tid & 63;
    const int wn   = tid >> 6;   // 0..3 (t); every wave owns all 128 co rows

    // XCD-aware swizzle (grid 2048 % 8 == 0 -> bijective)
    const int bid     = blockIdx.x;
    const int logical = ((bid & 7) << 8) | (bid >> 3);
    const int co_t = logical & 3;
    const int t_t  = (logical >> 2) & 7;
    const int b    = logical >> 5;

    const int co0 = co_t * BM;
    const int t0  = t_t * BN2;

    const unsigned short* xb = xbf + (size_t)b * T_IN * CIN;

    floatx4 acc[8][4];
#pragma unroll
    for (int m = 0; m < 8; ++m)
#pragma unroll
        for (int n = 0; n < 4; ++n)
            acc[m][n] = (floatx4)(0.0f);

    const int arow = lane & 15;
    const int c0   = lane >> 4;                       // logical 16B chunk
    const int aswz = ((c0 ^ ((arow >> 1) & 3)) << 3); // W read swizzle (elems)

    // ---- staging: W 2560 chunks (10/thread), X 1040 (4/thread + 16 tail) ---
    auto stage = [&](int sel, int ci0) {
#pragma unroll
        for (int it = 0; it < 10; ++it) {
            const int e  = tid + it * 256;
            const int kw = e >> 9;
            const int r  = e & 511;
            const int co = r >> 2;
            const int c8 = (((r & 3) ^ ((co >> 1) & 3)) << 3);
            gl_lds16(wbf + ((size_t)(kw * COUT + co0 + co)) * CIN + ci0 + c8,
                     &Wl[sel][e * 8]);
        }
#pragma unroll
        for (int it = 0; it < 4; ++it) {
            const int e  = tid + it * 256;
            const int t  = e >> 2;
            const int c8 = (((e & 3) ^ ((t >> 1) & 3)) << 3);
            gl_lds16(xb + (size_t)(t0 + t) * CIN + ci0 + c8, &Xl[sel][e * 8]);
        }
        if (tid < 16) {
            const int e  = 1024 + tid;
            const int t  = e >> 2;   // 256..259
            const int c8 = (((e & 3) ^ ((t >> 1) & 3)) << 3);
            int ts = t0 + t; if (ts > T_IN - 1) ts = T_IN - 1;  // feeds masked cols only
            gl_lds16(xb + (size_t)ts * CIN + ci0 + c8, &Xl[sel][e * 8]);
        }
    };

    // compute: per kw read af[8] + bfr[4] (12 ds_read_b128) then 32 MFMAs.
    auto compute = [&](int sel) {
#pragma unroll
        for (int kw = 0; kw < KW_; ++kw) {
            // X swizzle: row = wn*64+n*16+arow+kw -> (row>>1)&3 = ((arow+kw)>>1)&3
            const int bswz = ((c0 ^ (((arow + kw) >> 1) & 3)) << 3);
            short8 af[8], bfr[4];
#pragma unroll
            for (int m = 0; m < 8; ++m)
                af[m] = *reinterpret_cast<const short8*>(
                    &Wl[sel][(kw * BM + m * 16 + arow) * BK + aswz]);
#pragma unroll
            for (int n = 0; n < 4; ++n)
                bfr[n] = *reinterpret_cast<const short8*>(
                    &Xl[sel][(wn * 64 + n * 16 + arow + kw) * BK + bswz]);
            __builtin_amdgcn_s_setprio(1);
#pragma unroll
            for (int m = 0; m < 8; ++m)
#pragma unroll
                for (int n = 0; n < 4; ++n)
                    acc[m][n] = __builtin_amdgcn_mfma_f32_16x16x32_bf16(
                        af[m], bfr[n], acc[m][n], 0, 0, 0);
            __builtin_amdgcn_s_setprio(0);
        }
    };

    // ---- pipelined K-loop: 16 ci-tiles, 2x unrolled for static buffer sel ----
    stage(0, 0);
#pragma unroll 1
    for (int i = 0; i < 16; i += 2) {
        // even half: prefetch tile i+1 into buf1, compute tile i from buf0
        stage(1, (i + 1) * BK);
        asm volatile("s_waitcnt vmcnt(14)" ::: "memory");  // tile-i loads landed
        __builtin_amdgcn_sched_barrier(0);
        __builtin_amdgcn_s_barrier();
        __builtin_amdgcn_sched_barrier(0);
        compute(0);
        __builtin_amdgcn_s_barrier();                      // buf0 reads done
        __builtin_amdgcn_sched_barrier(0);

        // odd half: prefetch tile i+2 into buf0, compute tile i+1 from buf1
        if (i + 2 < 16) {
            stage(0, (i + 2) * BK);
            asm volatile("s_waitcnt vmcnt(14)" ::: "memory");
        } else {
            asm volatile("s_waitcnt vmcnt(0)" ::: "memory");
        }
        __builtin_amdgcn_sched_barrier(0);
        __builtin_amdgcn_s_barrier();
        __builtin_amdgcn_sched_barrier(0);
        compute(1);
        __builtin_amdgcn_s_barrier();                      // buf1 reads done
        __builtin_amdgcn_sched_barrier(0);
    }

    // ---- epilogue: D layout col = lane&15 (t), row = (lane>>4)*4 + r (co)
    const int colb = wn * 64 + (lane & 15);
    const int rowb = (lane >> 4) * 4;
    float* outp = out + ((size_t)b * COUT + co0) * TOUT + t0;
#pragma unroll
    for (int m = 0; m < 8; ++m) {
        const int row0 = rowb + m * 16;
        float bv[4];
#pragma unroll
        for (int r = 0; r < 4; ++r) bv[r] = bias[co0 + row0 + r];
#pragma unroll
        for (int n = 0; n < 4; ++n) {
            const int col = colb + n * 16;
            if (t0 + col < TOUT) {
#pragma unroll
                for (int r = 0; r < 4; ++r)
                    outp[(size_t)(row0 + r) * TOUT + col] = acc[m][n][r] + bv[r];
            }
        }
    }
}

// ---------------- fallback (round-1 kernel, used if ws too small) -----------
#define PAD   40
__global__ __launch_bounds__(256, 2)
void tdl_conv_mfma(const float* __restrict__ x,
                   const float* __restrict__ w,
                   const float* __restrict__ bias,
                   float* __restrict__ out)
{
    __shared__ __align__(16) unsigned short Wlds[KW_][BM][PAD];
    __shared__ __align__(16) unsigned short Xlds[BM + 4][PAD];

    const int tid  = threadIdx.x;
    const int lane = tid & 63;
    const int wid  = tid >> 6;
    const int wm   = wid >> 1;
    const int wn   = wid & 1;

    const int bid  = blockIdx.x;
    const int co_t = bid & 3;
    const int t_t  = (bid >> 2) & 15;
    const int b    = bid >> 6;

    const int co0 = co_t * BM;
    const int t0  = t_t * BM;

    floatx4 acc[4][4];
#pragma unroll
    for (int m = 0; m < 4; ++m)
#pragma unroll
        for (int n = 0; n < 4; ++n)
            acc[m][n] = (floatx4)(0.0f);

    const float* xb = x + (size_t)b * CIN * T_IN;
    const int arow = lane & 15;
    const int k8   = (lane >> 4) * 8;

    for (int ci0 = 0; ci0 < CIN; ci0 += BK) {
        for (int e = tid; e < BK * 33; e += 256) {
            const int ci = e / 33;
            const int q  = e - ci * 33;
            const int tt = q * 4;
            const int tg = t0 + tt;
            float4 v = make_float4(0.f, 0.f, 0.f, 0.f);
            if (tg < T_IN)
                v = *reinterpret_cast<const float4*>(xb + (size_t)(ci0 + ci) * T_IN + tg);
            Xlds[tt + 0][ci] = f2bf(v.x);
            Xlds[tt + 1][ci] = f2bf(v.y);
            Xlds[tt + 2][ci] = f2bf(v.z);
            Xlds[tt + 3][ci] = f2bf(v.w);
        }
        for (int e = tid; e < BM * 40; e += 256) {
            const int co = e / 40;
            const int q  = e - co * 40;
            const float4 v = *reinterpret_cast<const float4*>(
                w + (size_t)(co0 + co) * (CIN * KW_) + ci0 * KW_ + q * 4);
            const int m0 = q * 4;
            Wlds[(m0    ) % 5][co][(m0    ) / 5] = f2bf(v.x);
            Wlds[(m0 + 1) % 5][co][(m0 + 1) / 5] = f2bf(v.y);
            Wlds[(m0 + 2) % 5][co][(m0 + 2) / 5] = f2bf(v.z);
            Wlds[(m0 + 3) % 5][co][(m0 + 3) / 5] = f2bf(v.w);
        }
        __syncthreads();
#pragma unroll
        for (int kw = 0; kw < KW_; ++kw) {
            short8 afrag[4], bfrag[4];
#pragma unroll
            for (int m = 0; m < 4; ++m)
                afrag[m] = *reinterpret_cast<const short8*>(
                    &Wlds[kw][wm * 64 + m * 16 + arow][k8]);
#pragma unroll
            for (int n = 0; n < 4; ++n)
                bfrag[n] = *reinterpret_cast<const short8*>(
                    &Xlds[wn * 64 + n * 16 + arow + kw][k8]);
#pragma unroll
            for (int m = 0; m < 4; ++m)
#pragma unroll
                for (int n = 0; n < 4; ++n)
                    acc[m][n] = __builtin_amdgcn_mfma_f32_16x16x32_bf16(
                        afrag[m], bfrag[n], acc[m][n], 0, 0, 0);
        }
        __syncthreads();
    }

    const int colb = wn * 64 + (lane & 15);
    const int rowb = wm * 64 + (lane >> 4) * 4;
    float* outp = out + ((size_t)b * COUT + co0) * TOUT + t0;
#pragma unroll
    for (int m = 0; m < 4; ++m) {
        const int row0 = rowb + m * 16;
        float bv[4];
#pragma unroll
        for (int r = 0; r < 4; ++r) bv[r] = bias[co0 + row0 + r];
#pragma unroll
        for (int n = 0; n < 4; ++n) {
            const int col = colb + n * 16;
            if (t0 + col < TOUT) {
#pragma unroll
                for (int r = 0; r < 4; ++r)
                    outp[(size_t)(row0 + r) * TOUT + col] = acc[m][n][r] + bv[r];
            }
        }
    }
}

extern "C" void kernel_launch(void* const* d_in, const int* in_sizes, int n_in,
                              void* d_out, int out_size, void* d_ws, size_t ws_size,
                              hipStream_t stream) {
    const float* x    = (const float*)d_in[0];
    const float* w    = (const float*)d_in[1];
    const float* bias = (const float*)d_in[2];
    float* out        = (float*)d_out;

    const size_t xbf_elems = (size_t)B_SZ * T_IN * CIN;
    const size_t wbf_elems = (size_t)KW_ * COUT * CIN;
    const size_t need = (xbf_elems + wbf_elems) * sizeof(unsigned short);

    if (ws_size >= need) {
        unsigned short* xbf = (unsigned short*)d_ws;
        unsigned short* wbf = xbf + xbf_elems;

        wconv_kernel<<<(COUT * CIN * KW_ + 255) / 256, 256, 0, stream>>>(w, wbf);
        dim3 tg(T_IN / 64, CIN / 64, B_SZ);
        xtrans_kernel<<<tg, 256, 0, stream>>>(x, xbf);
        // grid: 4 co-tiles * 8 t-tiles * 64 batches = 2048 blocks, 1/CU
        tdl_conv_db<<<4 * 8 * B_SZ, 256, 0, stream>>>(xbf, wbf, bias, out);
    } else {
        tdl_conv_mfma<<<4 * 16 * B_SZ, 256, 0, stream>>>(x, w, bias, out);
    }
}

// Round 7
// 403.067 us; speedup vs baseline: 1.6061x; 1.0938x over previous
//
#include <hip/hip_runtime.h>
#include <hip/hip_bf16.h>

// Problem constants
#define B_SZ  64
#define CIN   512
#define T_IN  2048
#define COUT  512
#define KW_   5
#define TOUT  2044

// Main kernel (round 7): dbuf pipeline + TLP restored.
// 512 threads (8 waves, 2/SIMD), tile 128(co) x 256(t), BK=32.
// Wave grid 2(co) x 4(t): each wave owns 64x64 -> acc[4][4] = 64 regs.
//
// SESSION LEDGER: dbuf needs BOTH (a) no spill and (b) >=2 waves/SIMD.
//   R2/R3: acc=128 @ 2 waves/SIMD (256 budget) -> spill (b ok, a fail).
//   R6:    acc=128 @ 1 wave/SIMD (512 budget) -> no spill but zero TLP,
//          ds_read->MFMA chain exposed, MfmaUtil 38% (a ok, b fail).
//   HERE:  acc=64 @ 2 waves/SIMD: demand ~150 << 256. Both hold.
// Cost: reads/MFMA 0.5 (8 reads / 16 MFMA per kw) vs 0.375 at 128x64 tile;
// per-CU LDS-read floor ~205us vs MFMA 165us -> LDS-read-bound, ~230us
// expected (vs 303 for the R0 2-phase and 397 for R6).
//
// Pipeline (T3+T4), identical to R6 except wave decomposition: stage(buf0);
// loop{ stage(buf^1,next); s_waitcnt vmcnt(7); s_barrier; compute(buf);
// s_barrier; }. Per-wave staging ops: 5 W + 2 X = 7 (wave0 +1 exec-masked
// tail; FIFO vmcnt -> vmcnt(7) conservative). vmcnt(0) only at last tile.
// LDS XOR swizzle (chunk ^= (row>>1)&3) on BOTH global_load_lds SOURCE and
// ds_read address (rule #21); SQ_LDS_BANK_CONFLICT == 0 verified.
#define BM    128
#define BN2   256
#define BK    32

typedef __attribute__((ext_vector_type(8))) short   short8;
typedef __attribute__((ext_vector_type(4))) float   floatx4;

__device__ __forceinline__ unsigned short f2bf(float f) {
    unsigned int u = __builtin_bit_cast(unsigned int, f);
    u += 0x7fffu + ((u >> 16) & 1u);   // RNE
    return (unsigned short)(u >> 16);
}

__device__ __forceinline__ void gl_lds16(const void* g, void* l) {
    __builtin_amdgcn_global_load_lds(
        (const __attribute__((address_space(1))) unsigned int*)g,
        (__attribute__((address_space(3))) unsigned int*)l, 16, 0, 0);
}

// ---------------- pre-kernel 1: W fp32 [co][ci][kw] -> bf16 [kw][co][ci] ----
__global__ __launch_bounds__(256)
void wconv_kernel(const float* __restrict__ w, unsigned short* __restrict__ wbf) {
    int i = blockIdx.x * 256 + threadIdx.x;
    if (i < COUT * CIN * KW_) {
        int kw = i % KW_;
        int r  = i / KW_;
        int ci = r % CIN;
        int co = r / CIN;
        wbf[((size_t)kw * COUT + co) * CIN + ci] = f2bf(w[i]);
    }
}

// ---------------- pre-kernel 2: X fp32 [b][ci][t] -> bf16 [b][t][ci] --------
__global__ __launch_bounds__(256)
void xtrans_kernel(const float* __restrict__ x, unsigned short* __restrict__ xbf) {
    __shared__ float tile[64][68];
    const int t0  = blockIdx.x * 64;
    const int ci0 = blockIdx.y * 64;
    const int b   = blockIdx.z;
    const int tid = threadIdx.x;

    const float* xb = x + ((size_t)b * CIN + ci0) * T_IN + t0;
    const int cl = tid >> 4, fc = tid & 15;
#pragma unroll
    for (int p = 0; p < 4; ++p) {
        float4 v = *reinterpret_cast<const float4*>(xb + (size_t)(cl + p * 16) * T_IN + fc * 4);
        *reinterpret_cast<float4*>(&tile[cl + p * 16][fc * 4]) = v;
    }
    __syncthreads();

    const int tl = tid >> 2, cg = (tid & 3) * 16;
    unsigned short tmp[16];
#pragma unroll
    for (int j = 0; j < 16; ++j) tmp[j] = f2bf(tile[cg + j][tl]);
    unsigned short* dst = xbf + ((size_t)b * T_IN + t0 + tl) * CIN + ci0 + cg;
    *reinterpret_cast<short8*>(dst)     = *reinterpret_cast<short8*>(tmp);
    *reinterpret_cast<short8*>(dst + 8) = *reinterpret_cast<short8*>(tmp + 8);
}

// --- main kernel: 128x256 block, 8 waves of 64x64, dbuf + counted vmcnt -----
__global__ __launch_bounds__(512, 2)
void tdl_conv_db8(const unsigned short* __restrict__ xbf,
                  const unsigned short* __restrict__ wbf,
                  const float* __restrict__ bias,
                  float* __restrict__ out)
{
    // Wl: 2 x [5][128][32] bf16 = 81920 B ; Xl: 2 x [260][32] bf16 = 33280 B
    // total 115200 B -> 1 block/CU (8 waves, 2/SIMD, 256 regs/wave)
    __shared__ __align__(16) unsigned short Wl[2][KW_ * BM * BK];
    __shared__ __align__(16) unsigned short Xl[2][(BN2 + 4) * BK];

    const int tid  = threadIdx.x;
    const int lane = tid & 63;
    const int wid  = tid >> 6;   // 0..7
    const int wm   = wid >> 2;   // 0..1: co half (64 rows)
    const int wt   = wid & 3;    // 0..3: t quarter (64 cols)

    // XCD-aware swizzle (grid 2048 % 8 == 0 -> bijective)
    const int bid     = blockIdx.x;
    const int logical = ((bid & 7) << 8) | (bid >> 3);
    const int co_t = logical & 3;
    const int t_t  = (logical >> 2) & 7;
    const int b    = logical >> 5;

    const int co0 = co_t * BM;
    const int t0  = t_t * BN2;

    const unsigned short* xb = xbf + (size_t)b * T_IN * CIN;

    floatx4 acc[4][4];
#pragma unroll
    for (int m = 0; m < 4; ++m)
#pragma unroll
        for (int n = 0; n < 4; ++n)
            acc[m][n] = (floatx4)(0.0f);

    const int arow = lane & 15;
    const int c0   = lane >> 4;                       // logical 16B chunk
    const int aswz = ((c0 ^ ((arow >> 1) & 3)) << 3); // W read swizzle (elems)

    // ---- staging: W 2560 chunks (5/thread), X 1040 (2/thread + 16 tail) ----
    auto stage = [&](int sel, int ci0) {
#pragma unroll
        for (int it = 0; it < 5; ++it) {
            const int e  = tid + it * 512;
            const int kw = e >> 9;
            const int r  = e & 511;
            const int co = r >> 2;
            const int c8 = (((r & 3) ^ ((co >> 1) & 3)) << 3);
            gl_lds16(wbf + ((size_t)(kw * COUT + co0 + co)) * CIN + ci0 + c8,
                     &Wl[sel][e * 8]);
        }
#pragma unroll
        for (int it = 0; it < 2; ++it) {
            const int e  = tid + it * 512;
            const int t  = e >> 2;
            const int c8 = (((e & 3) ^ ((t >> 1) & 3)) << 3);
            gl_lds16(xb + (size_t)(t0 + t) * CIN + ci0 + c8, &Xl[sel][e * 8]);
        }
        if (tid < 16) {
            const int e  = 1024 + tid;
            const int t  = e >> 2;   // 256..259
            const int c8 = (((e & 3) ^ ((t >> 1) & 3)) << 3);
            int ts = t0 + t; if (ts > T_IN - 1) ts = T_IN - 1;  // feeds masked cols only
            gl_lds16(xb + (size_t)ts * CIN + ci0 + c8, &Xl[sel][e * 8]);
        }
    };

    // compute: per kw read af[4] + bfr[4] (8 ds_read_b128) then 16 MFMAs.
    auto compute = [&](int sel) {
#pragma unroll
        for (int kw = 0; kw < KW_; ++kw) {
            // row = wt*64+n*16+arow+kw -> (row>>1)&3 = ((arow+kw)>>1)&3
            const int bswz = ((c0 ^ (((arow + kw) >> 1) & 3)) << 3);
            short8 af[4], bfr[4];
#pragma unroll
            for (int m = 0; m < 4; ++m)
                af[m] = *reinterpret_cast<const short8*>(
                    &Wl[sel][(kw * BM + wm * 64 + m * 16 + arow) * BK + aswz]);
#pragma unroll
            for (int n = 0; n < 4; ++n)
                bfr[n] = *reinterpret_cast<const short8*>(
                    &Xl[sel][(wt * 64 + n * 16 + arow + kw) * BK + bswz]);
            __builtin_amdgcn_s_setprio(1);
#pragma unroll
            for (int m = 0; m < 4; ++m)
#pragma unroll
                for (int n = 0; n < 4; ++n)
                    acc[m][n] = __builtin_amdgcn_mfma_f32_16x16x32_bf16(
                        af[m], bfr[n], acc[m][n], 0, 0, 0);
            __builtin_amdgcn_s_setprio(0);
        }
    };

    // ---- pipelined K-loop: 16 ci-tiles, 2x unrolled for static buffer sel ----
    stage(0, 0);
#pragma unroll 1
    for (int i = 0; i < 16; i += 2) {
        // even half: prefetch tile i+1 into buf1, compute tile i from buf0
        stage(1, (i + 1) * BK);
        asm volatile("s_waitcnt vmcnt(7)" ::: "memory");   // tile-i loads landed
        __builtin_amdgcn_sched_barrier(0);
        __builtin_amdgcn_s_barrier();
        __builtin_amdgcn_sched_barrier(0);
        compute(0);
        __builtin_amdgcn_s_barrier();                      // buf0 reads done
        __builtin_amdgcn_sched_barrier(0);

        // odd half: prefetch tile i+2 into buf0, compute tile i+1 from buf1
        if (i + 2 < 16) {
            stage(0, (i + 2) * BK);
            asm volatile("s_waitcnt vmcnt(7)" ::: "memory");
        } else {
            asm volatile("s_waitcnt vmcnt(0)" ::: "memory");
        }
        __builtin_amdgcn_sched_barrier(0);
        __builtin_amdgcn_s_barrier();
        __builtin_amdgcn_sched_barrier(0);
        compute(1);
        __builtin_amdgcn_s_barrier();                      // buf1 reads done
        __builtin_amdgcn_sched_barrier(0);
    }

    // ---- epilogue: D layout col = lane&15 (t), row = (lane>>4)*4 + r (co)
    const int colb = wt * 64 + (lane & 15);
    const int rowb = wm * 64 + (lane >> 4) * 4;
    float* outp = out + ((size_t)b * COUT + co0) * TOUT + t0;
#pragma unroll
    for (int m = 0; m < 4; ++m) {
        const int row0 = rowb + m * 16;
        float bv[4];
#pragma unroll
        for (int r = 0; r < 4; ++r) bv[r] = bias[co0 + row0 + r];
#pragma unroll
        for (int n = 0; n < 4; ++n) {
            const int col = colb + n * 16;
            if (t0 + col < TOUT) {
#pragma unroll
                for (int r = 0; r < 4; ++r)
                    outp[(size_t)(row0 + r) * TOUT + col] = acc[m][n][r] + bv[r];
            }
        }
    }
}

// ---------------- fallback (round-1 kernel, used if ws too small) -----------
#define PAD   40
__global__ __launch_bounds__(256, 2)
void tdl_conv_mfma(const float* __restrict__ x,
                   const float* __restrict__ w,
                   const float* __restrict__ bias,
                   float* __restrict__ out)
{
    __shared__ __align__(16) unsigned short Wlds[KW_][BM][PAD];
    __shared__ __align__(16) unsigned short Xlds[BM + 4][PAD];

    const int tid  = threadIdx.x;
    const int lane = tid & 63;
    const int wid  = tid >> 6;
    const int wm   = wid >> 1;
    const int wn   = wid & 1;

    const int bid  = blockIdx.x;
    const int co_t = bid & 3;
    const int t_t  = (bid >> 2) & 15;
    const int b    = bid >> 6;

    const int co0 = co_t * BM;
    const int t0  = t_t * BM;

    floatx4 acc[4][4];
#pragma unroll
    for (int m = 0; m < 4; ++m)
#pragma unroll
        for (int n = 0; n < 4; ++n)
            acc[m][n] = (floatx4)(0.0f);

    const float* xb = x + (size_t)b * CIN * T_IN;
    const int arow = lane & 15;
    const int k8   = (lane >> 4) * 8;

    for (int ci0 = 0; ci0 < CIN; ci0 += BK) {
        for (int e = tid; e < BK * 33; e += 256) {
            const int ci = e / 33;
            const int q  = e - ci * 33;
            const int tt = q * 4;
            const int tg = t0 + tt;
            float4 v = make_float4(0.f, 0.f, 0.f, 0.f);
            if (tg < T_IN)
                v = *reinterpret_cast<const float4*>(xb + (size_t)(ci0 + ci) * T_IN + tg);
            Xlds[tt + 0][ci] = f2bf(v.x);
            Xlds[tt + 1][ci] = f2bf(v.y);
            Xlds[tt + 2][ci] = f2bf(v.z);
            Xlds[tt + 3][ci] = f2bf(v.w);
        }
        for (int e = tid; e < BM * 40; e += 256) {
            const int co = e / 40;
            const int q  = e - co * 40;
            const float4 v = *reinterpret_cast<const float4*>(
                w + (size_t)(co0 + co) * (CIN * KW_) + ci0 * KW_ + q * 4);
            const int m0 = q * 4;
            Wlds[(m0    ) % 5][co][(m0    ) / 5] = f2bf(v.x);
            Wlds[(m0 + 1) % 5][co][(m0 + 1) / 5] = f2bf(v.y);
            Wlds[(m0 + 2) % 5][co][(m0 + 2) / 5] = f2bf(v.z);
            Wlds[(m0 + 3) % 5][co][(m0 + 3) / 5] = f2bf(v.w);
        }
        __syncthreads();
#pragma unroll
        for (int kw = 0; kw < KW_; ++kw) {
            short8 afrag[4], bfrag[4];
#pragma unroll
            for (int m = 0; m < 4; ++m)
                afrag[m] = *reinterpret_cast<const short8*>(
                    &Wlds[kw][wm * 64 + m * 16 + arow][k8]);
#pragma unroll
            for (int n = 0; n < 4; ++n)
                bfrag[n] = *reinterpret_cast<const short8*>(
                    &Xlds[wn * 64 + n * 16 + arow + kw][k8]);
#pragma unroll
            for (int m = 0; m < 4; ++m)
#pragma unroll
                for (int n = 0; n < 4; ++n)
                    acc[m][n] = __builtin_amdgcn_mfma_f32_16x16x32_bf16(
                        afrag[m], bfrag[n], acc[m][n], 0, 0, 0);
        }
        __syncthreads();
    }

    const int colb = wn * 64 + (lane & 15);
    const int rowb = wm * 64 + (lane >> 4) * 4;
    float* outp = out + ((size_t)b * COUT + co0) * TOUT + t0;
#pragma unroll
    for (int m = 0; m < 4; ++m) {
        const int row0 = rowb + m * 16;
        float bv[4];
#pragma unroll
        for (int r = 0; r < 4; ++r) bv[r] = bias[co0 + row0 + r];
#pragma unroll
        for (int n = 0; n < 4; ++n) {
            const int col = colb + n * 16;
            if (t0 + col < TOUT) {
#pragma unroll
                for (int r = 0; r < 4; ++r)
                    outp[(size_t)(row0 + r) * TOUT + col] = acc[m][n][r] + bv[r];
            }
        }
    }
}

extern "C" void kernel_launch(void* const* d_in, const int* in_sizes, int n_in,
                              void* d_out, int out_size, void* d_ws, size_t ws_size,
                              hipStream_t stream) {
    const float* x    = (const float*)d_in[0];
    const float* w    = (const float*)d_in[1];
    const float* bias = (const float*)d_in[2];
    float* out        = (float*)d_out;

    const size_t xbf_elems = (size_t)B_SZ * T_IN * CIN;
    const size_t wbf_elems = (size_t)KW_ * COUT * CIN;
    const size_t need = (xbf_elems + wbf_elems) * sizeof(unsigned short);

    if (ws_size >= need) {
        unsigned short* xbf = (unsigned short*)d_ws;
        unsigned short* wbf = xbf + xbf_elems;

        wconv_kernel<<<(COUT * CIN * KW_ + 255) / 256, 256, 0, stream>>>(w, wbf);
        dim3 tg(T_IN / 64, CIN / 64, B_SZ);
        xtrans_kernel<<<tg, 256, 0, stream>>>(x, xbf);
        // grid: 4 co-tiles * 8 t-tiles * 64 batches = 2048 blocks, 1/CU
        tdl_conv_db8<<<4 * 8 * B_SZ, 512, 0, stream>>>(xbf, wbf, bias, out);
    } else {
        tdl_conv_mfma<<<4 * 16 * B_SZ, 256, 0, stream>>>(x, w, bias, out);
    }
}

// Round 8
// 401.998 us; speedup vs baseline: 1.6103x; 1.0027x over previous
//
#include <hip/hip_runtime.h>
#include <hip/hip_bf16.h>

// Problem constants
#define B_SZ  64
#define CIN   512
#define T_IN  2048
#define COUT  512
#define KW_   5
#define TOUT  2044

// Main kernel (round 8): R7 geometry + kw-level register double-buffer.
// 512 threads (8 waves, 2/SIMD), tile 128(co) x 256(t), BK=32.
// Wave grid 2(co) x 4(t): each wave owns 64x64 -> acc[4][4] = 64 regs.
//
// R7 POST-MORTEM (beat arithmetic): 128 beats/CU x 6640 cyc; per beat MFMA
// needs ~3100 cyc, LDS ~3000 cyc; 6640 = SERIAL. Cause: per-kw
// "8 ds_reads -> lgkmcnt -> 16 MFMAs" chain with the MFMA cluster bracketed
// by s_setprio (SOPP = scheduler barrier: kw+1 reads can't hoist under kw
// MFMAs), and both waves/SIMD phase-locked by block barriers.
// FIX: (1) drop setprio (m190: hurts lockstep GEMM); (2) explicit A/B
// register double-buffer over kw -- issue kw+1's 8 ds_reads BEFORE kw's 16
// MFMAs (statically unrolled swap, rule #20). Target beat ~max(3100,3000).
//
// Pipeline (T3+T4) unchanged from R7: stage(buf0); loop{ stage(buf^1,next);
// s_waitcnt vmcnt(7); s_barrier; compute(buf); s_barrier; }. Per-wave
// staging ops: 5 W + 2 X = 7 (wave0 +1 exec-masked tail; FIFO vmcnt ->
// vmcnt(7) conservative). vmcnt(0) only at last tile.
// LDS XOR swizzle (chunk ^= (row>>1)&3) on BOTH global_load_lds SOURCE and
// ds_read address (rule #21); SQ_LDS_BANK_CONFLICT == 0 verified.
#define BM    128
#define BN2   256
#define BK    32

typedef __attribute__((ext_vector_type(8))) short   short8;
typedef __attribute__((ext_vector_type(4))) float   floatx4;

__device__ __forceinline__ unsigned short f2bf(float f) {
    unsigned int u = __builtin_bit_cast(unsigned int, f);
    u += 0x7fffu + ((u >> 16) & 1u);   // RNE
    return (unsigned short)(u >> 16);
}

__device__ __forceinline__ void gl_lds16(const void* g, void* l) {
    __builtin_amdgcn_global_load_lds(
        (const __attribute__((address_space(1))) unsigned int*)g,
        (__attribute__((address_space(3))) unsigned int*)l, 16, 0, 0);
}

// ---------------- pre-kernel 1: W fp32 [co][ci][kw] -> bf16 [kw][co][ci] ----
__global__ __launch_bounds__(256)
void wconv_kernel(const float* __restrict__ w, unsigned short* __restrict__ wbf) {
    int i = blockIdx.x * 256 + threadIdx.x;
    if (i < COUT * CIN * KW_) {
        int kw = i % KW_;
        int r  = i / KW_;
        int ci = r % CIN;
        int co = r / CIN;
        wbf[((size_t)kw * COUT + co) * CIN + ci] = f2bf(w[i]);
    }
}

// ---------------- pre-kernel 2: X fp32 [b][ci][t] -> bf16 [b][t][ci] --------
__global__ __launch_bounds__(256)
void xtrans_kernel(const float* __restrict__ x, unsigned short* __restrict__ xbf) {
    __shared__ float tile[64][68];
    const int t0  = blockIdx.x * 64;
    const int ci0 = blockIdx.y * 64;
    const int b   = blockIdx.z;
    const int tid = threadIdx.x;

    const float* xb = x + ((size_t)b * CIN + ci0) * T_IN + t0;
    const int cl = tid >> 4, fc = tid & 15;
#pragma unroll
    for (int p = 0; p < 4; ++p) {
        float4 v = *reinterpret_cast<const float4*>(xb + (size_t)(cl + p * 16) * T_IN + fc * 4);
        *reinterpret_cast<float4*>(&tile[cl + p * 16][fc * 4]) = v;
    }
    __syncthreads();

    const int tl = tid >> 2, cg = (tid & 3) * 16;
    unsigned short tmp[16];
#pragma unroll
    for (int j = 0; j < 16; ++j) tmp[j] = f2bf(tile[cg + j][tl]);
    unsigned short* dst = xbf + ((size_t)b * T_IN + t0 + tl) * CIN + ci0 + cg;
    *reinterpret_cast<short8*>(dst)     = *reinterpret_cast<short8*>(tmp);
    *reinterpret_cast<short8*>(dst + 8) = *reinterpret_cast<short8*>(tmp + 8);
}

// --- main kernel: 128x256 block, 8 waves of 64x64, dbuf + kw reg-pipeline ---
__global__ __launch_bounds__(512, 2)
void tdl_conv_db8(const unsigned short* __restrict__ xbf,
                  const unsigned short* __restrict__ wbf,
                  const float* __restrict__ bias,
                  float* __restrict__ out)
{
    // Wl: 2 x [5][128][32] bf16 = 81920 B ; Xl: 2 x [260][32] bf16 = 33280 B
    // total 115200 B -> 1 block/CU (8 waves, 2/SIMD, 256 regs/wave)
    __shared__ __align__(16) unsigned short Wl[2][KW_ * BM * BK];
    __shared__ __align__(16) unsigned short Xl[2][(BN2 + 4) * BK];

    const int tid  = threadIdx.x;
    const int lane = tid & 63;
    const int wid  = tid >> 6;   // 0..7
    const int wm   = wid >> 2;   // 0..1: co half (64 rows)
    const int wt   = wid & 3;    // 0..3: t quarter (64 cols)

    // XCD-aware swizzle (grid 2048 % 8 == 0 -> bijective)
    const int bid     = blockIdx.x;
    const int logical = ((bid & 7) << 8) | (bid >> 3);
    const int co_t = logical & 3;
    const int t_t  = (logical >> 2) & 7;
    const int b    = logical >> 5;

    const int co0 = co_t * BM;
    const int t0  = t_t * BN2;

    const unsigned short* xb = xbf + (size_t)b * T_IN * CIN;

    floatx4 acc[4][4];
#pragma unroll
    for (int m = 0; m < 4; ++m)
#pragma unroll
        for (int n = 0; n < 4; ++n)
            acc[m][n] = (floatx4)(0.0f);

    const int arow = lane & 15;
    const int c0   = lane >> 4;                       // logical 16B chunk
    const int aswz = ((c0 ^ ((arow >> 1) & 3)) << 3); // W read swizzle (elems)

    // ---- staging: W 2560 chunks (5/thread), X 1040 (2/thread + 16 tail) ----
    auto stage = [&](int sel, int ci0) {
#pragma unroll
        for (int it = 0; it < 5; ++it) {
            const int e  = tid + it * 512;
            const int kw = e >> 9;
            const int r  = e & 511;
            const int co = r >> 2;
            const int c8 = (((r & 3) ^ ((co >> 1) & 3)) << 3);
            gl_lds16(wbf + ((size_t)(kw * COUT + co0 + co)) * CIN + ci0 + c8,
                     &Wl[sel][e * 8]);
        }
#pragma unroll
        for (int it = 0; it < 2; ++it) {
            const int e  = tid + it * 512;
            const int t  = e >> 2;
            const int c8 = (((e & 3) ^ ((t >> 1) & 3)) << 3);
            gl_lds16(xb + (size_t)(t0 + t) * CIN + ci0 + c8, &Xl[sel][e * 8]);
        }
        if (tid < 16) {
            const int e  = 1024 + tid;
            const int t  = e >> 2;   // 256..259
            const int c8 = (((e & 3) ^ ((t >> 1) & 3)) << 3);
            int ts = t0 + t; if (ts > T_IN - 1) ts = T_IN - 1;  // feeds masked cols only
            gl_lds16(xb + (size_t)ts * CIN + ci0 + c8, &Xl[sel][e * 8]);
        }
    };

    // fragment loads for one kw (4 W + 4 X ds_read_b128)
    auto loadW = [&](int sel, int kw, short8* af) {
#pragma unroll
        for (int m = 0; m < 4; ++m)
            af[m] = *reinterpret_cast<const short8*>(
                &Wl[sel][(kw * BM + wm * 64 + m * 16 + arow) * BK + aswz]);
    };
    auto loadX = [&](int sel, int kw, short8* bf) {
        // row = wt*64+n*16+arow+kw -> (row>>1)&3 = ((arow+kw)>>1)&3
        const int bswz = ((c0 ^ (((arow + kw) >> 1) & 3)) << 3);
#pragma unroll
        for (int n = 0; n < 4; ++n)
            bf[n] = *reinterpret_cast<const short8*>(
                &Xl[sel][(wt * 64 + n * 16 + arow + kw) * BK + bswz]);
    };

    // compute: kw-level A/B register double-buffer. kw+1's 8 ds_reads are
    // issued BEFORE kw's 16 MFMAs so the scheduler can overlap LDS and MFMA
    // pipes. No setprio (SOPP scheduling barrier defeats the interleave;
    // m190: setprio hurts lockstep GEMM anyway). Fully unrolled -> all
    // pointer selects are compile-time (rule #20).
    auto compute = [&](int sel) {
        short8 afA[4], bfA[4], afB[4], bfB[4];
        loadW(sel, 0, afA);
        loadX(sel, 0, bfA);
#pragma unroll
        for (int kw = 0; kw < KW_; ++kw) {
            short8* afc = (kw & 1) ? afB : afA;
            short8* bfc = (kw & 1) ? bfB : bfA;
            short8* afn = (kw & 1) ? afA : afB;
            short8* bfn = (kw & 1) ? bfA : bfB;
            if (kw + 1 < KW_) {
                loadW(sel, kw + 1, afn);
                loadX(sel, kw + 1, bfn);
            }
#pragma unroll
            for (int m = 0; m < 4; ++m)
#pragma unroll
                for (int n = 0; n < 4; ++n)
                    acc[m][n] = __builtin_amdgcn_mfma_f32_16x16x32_bf16(
                        afc[m], bfc[n], acc[m][n], 0, 0, 0);
        }
    };

    // ---- pipelined K-loop: 16 ci-tiles, 2x unrolled for static buffer sel ----
    stage(0, 0);
#pragma unroll 1
    for (int i = 0; i < 16; i += 2) {
        // even half: prefetch tile i+1 into buf1, compute tile i from buf0
        stage(1, (i + 1) * BK);
        asm volatile("s_waitcnt vmcnt(7)" ::: "memory");   // tile-i loads landed
        __builtin_amdgcn_sched_barrier(0);
        __builtin_amdgcn_s_barrier();
        __builtin_amdgcn_sched_barrier(0);
        compute(0);
        __builtin_amdgcn_s_barrier();                      // buf0 reads done
        __builtin_amdgcn_sched_barrier(0);

        // odd half: prefetch tile i+2 into buf0, compute tile i+1 from buf1
        if (i + 2 < 16) {
            stage(0, (i + 2) * BK);
            asm volatile("s_waitcnt vmcnt(7)" ::: "memory");
        } else {
            asm volatile("s_waitcnt vmcnt(0)" ::: "memory");
        }
        __builtin_amdgcn_sched_barrier(0);
        __builtin_amdgcn_s_barrier();
        __builtin_amdgcn_sched_barrier(0);
        compute(1);
        __builtin_amdgcn_s_barrier();                      // buf1 reads done
        __builtin_amdgcn_sched_barrier(0);
    }

    // ---- epilogue: D layout col = lane&15 (t), row = (lane>>4)*4 + r (co)
    const int colb = wt * 64 + (lane & 15);
    const int rowb = wm * 64 + (lane >> 4) * 4;
    float* outp = out + ((size_t)b * COUT + co0) * TOUT + t0;
#pragma unroll
    for (int m = 0; m < 4; ++m) {
        const int row0 = rowb + m * 16;
        float bv[4];
#pragma unroll
        for (int r = 0; r < 4; ++r) bv[r] = bias[co0 + row0 + r];
#pragma unroll
        for (int n = 0; n < 4; ++n) {
            const int col = colb + n * 16;
            if (t0 + col < TOUT) {
#pragma unroll
                for (int r = 0; r < 4; ++r)
                    outp[(size_t)(row0 + r) * TOUT + col] = acc[m][n][r] + bv[r];
            }
        }
    }
}

// ---------------- fallback (round-1 kernel, used if ws too small) -----------
#define PAD   40
__global__ __launch_bounds__(256, 2)
void tdl_conv_mfma(const float* __restrict__ x,
                   const float* __restrict__ w,
                   const float* __restrict__ bias,
                   float* __restrict__ out)
{
    __shared__ __align__(16) unsigned short Wlds[KW_][BM][PAD];
    __shared__ __align__(16) unsigned short Xlds[BM + 4][PAD];

    const int tid  = threadIdx.x;
    const int lane = tid & 63;
    const int wid  = tid >> 6;
    const int wm   = wid >> 1;
    const int wn   = wid & 1;

    const int bid  = blockIdx.x;
    const int co_t = bid & 3;
    const int t_t  = (bid >> 2) & 15;
    const int b    = bid >> 6;

    const int co0 = co_t * BM;
    const int t0  = t_t * BM;

    floatx4 acc[4][4];
#pragma unroll
    for (int m = 0; m < 4; ++m)
#pragma unroll
        for (int n = 0; n < 4; ++n)
            acc[m][n] = (floatx4)(0.0f);

    const float* xb = x + (size_t)b * CIN * T_IN;
    const int arow = lane & 15;
    const int k8   = (lane >> 4) * 8;

    for (int ci0 = 0; ci0 < CIN; ci0 += BK) {
        for (int e = tid; e < BK * 33; e += 256) {
            const int ci = e / 33;
            const int q  = e - ci * 33;
            const int tt = q * 4;
            const int tg = t0 + tt;
            float4 v = make_float4(0.f, 0.f, 0.f, 0.f);
            if (tg < T_IN)
                v = *reinterpret_cast<const float4*>(xb + (size_t)(ci0 + ci) * T_IN + tg);
            Xlds[tt + 0][ci] = f2bf(v.x);
            Xlds[tt + 1][ci] = f2bf(v.y);
            Xlds[tt + 2][ci] = f2bf(v.z);
            Xlds[tt + 3][ci] = f2bf(v.w);
        }
        for (int e = tid; e < BM * 40; e += 256) {
            const int co = e / 40;
            const int q  = e - co * 40;
            const float4 v = *reinterpret_cast<const float4*>(
                w + (size_t)(co0 + co) * (CIN * KW_) + ci0 * KW_ + q * 4);
            const int m0 = q * 4;
            Wlds[(m0    ) % 5][co][(m0    ) / 5] = f2bf(v.x);
            Wlds[(m0 + 1) % 5][co][(m0 + 1) / 5] = f2bf(v.y);
            Wlds[(m0 + 2) % 5][co][(m0 + 2) / 5] = f2bf(v.z);
            Wlds[(m0 + 3) % 5][co][(m0 + 3) / 5] = f2bf(v.w);
        }
        __syncthreads();
#pragma unroll
        for (int kw = 0; kw < KW_; ++kw) {
            short8 afrag[4], bfrag[4];
#pragma unroll
            for (int m = 0; m < 4; ++m)
                afrag[m] = *reinterpret_cast<const short8*>(
                    &Wlds[kw][wm * 64 + m * 16 + arow][k8]);
#pragma unroll
            for (int n = 0; n < 4; ++n)
                bfrag[n] = *reinterpret_cast<const short8*>(
                    &Xlds[wn * 64 + n * 16 + arow + kw][k8]);
#pragma unroll
            for (int m = 0; m < 4; ++m)
#pragma unroll
                for (int n = 0; n < 4; ++n)
                    acc[m][n] = __builtin_amdgcn_mfma_f32_16x16x32_bf16(
                        afrag[m], bfrag[n], acc[m][n], 0, 0, 0);
        }
        __syncthreads();
    }

    const int colb = wn * 64 + (lane & 15);
    const int rowb = wm * 64 + (lane >> 4) * 4;
    float* outp = out + ((size_t)b * COUT + co0) * TOUT + t0;
#pragma unroll
    for (int m = 0; m < 4; ++m) {
        const int row0 = rowb + m * 16;
        float bv[4];
#pragma unroll
        for (int r = 0; r < 4; ++r) bv[r] = bias[co0 + row0 + r];
#pragma unroll
        for (int n = 0; n < 4; ++n) {
            const int col = colb + n * 16;
            if (t0 + col < TOUT) {
#pragma unroll
                for (int r = 0; r < 4; ++r)
                    outp[(size_t)(row0 + r) * TOUT + col] = acc[m][n][r] + bv[r];
            }
        }
    }
}

extern "C" void kernel_launch(void* const* d_in, const int* in_sizes, int n_in,
                              void* d_out, int out_size, void* d_ws, size_t ws_size,
                              hipStream_t stream) {
    const float* x    = (const float*)d_in[0];
    const float* w    = (const float*)d_in[1];
    const float* bias = (const float*)d_in[2];
    float* out        = (float*)d_out;

    const size_t xbf_elems = (size_t)B_SZ * T_IN * CIN;
    const size_t wbf_elems = (size_t)KW_ * COUT * CIN;
    const size_t need = (xbf_elems + wbf_elems) * sizeof(unsigned short);

    if (ws_size >= need) {
        unsigned short* xbf = (unsigned short*)d_ws;
        unsigned short* wbf = xbf + xbf_elems;

        wconv_kernel<<<(COUT * CIN * KW_ + 255) / 256, 256, 0, stream>>>(w, wbf);
        dim3 tg(T_IN / 64, CIN / 64, B_SZ);
        xtrans_kernel<<<tg, 256, 0, stream>>>(x, xbf);
        // grid: 4 co-tiles * 8 t-tiles * 64 batches = 2048 blocks, 1/CU
        tdl_conv_db8<<<4 * 8 * B_SZ, 512, 0, stream>>>(xbf, wbf, bias, out);
    } else {
        tdl_conv_mfma<<<4 * 16 * B_SZ, 256, 0, stream>>>(x, w, bias, out);
    }
}

// Round 9
// 388.354 us; speedup vs baseline: 1.6669x; 1.0351x over previous
//
#include <hip/hip_runtime.h>
#include <hip/hip_bf16.h>

// Problem constants
#define B_SZ  64
#define CIN   512
#define T_IN  2048
#define COUT  512
#define KW_   5
#define TOUT  2044

// Main kernel (round 9): R3 geometry with R8's lean body.
// 512 threads (8 waves, 2/SIMD), tile 128(co) x 512(t), BK=32.
// Every wave owns all 128 co x 64 t: acc[8][4] = 128 AGPR.
//
// R8 POST-MORTEM (beat model, staging writes priced): per 640-MFMA beat:
// MFMA 3100 cyc; LDS port = 320 ds_read_b128 x 12 + ~1800 cyc of gl_lds
// staging writes ~= 5640 ~= measured 6590 beat -> LDS-PORT-BOUND (MfmaUtil
// 44% = 3100/6590). R7->R8 null => schedule/ILP is not the constraint.
// Lever: LDS traffic per MFMA. 128x64 wave tile: 12 reads / 32 MFMA = 0.375
// (vs 0.5) and 2x work per beat amortizes fixed overhead. Per 1280-MFMA
// beat: MFMA 6200, LDS ~= 480x12 + 2300 = 8060 -> ~39% less port time/work.
//
// REGISTER LEDGER: R3 (same geometry) spilled ~3 regs -- caused by setprio
// + split-half + heavy staging state, NOT the geometry: R8 proved this
// compute needs only ~28 non-frag arch regs (92 total w/ 64 frag regs).
// Here: 48 frag + ~30 base ~= 80-100 arch << 128 cap (launch_bounds(512,2),
// acc in AGPRs). No setprio (m190 + R7), no A/B kw banking (R8 null).
//
// Pipeline (T3+T4, verified in R2/R3): stage(buf0); loop{ stage(buf^1,next);
// s_waitcnt vmcnt(9); s_barrier; compute(buf); s_barrier; }. Per-wave
// staging ops: 5 W + 4 X = 9 (wave0 +1 exec-masked tail; FIFO vmcnt ->
// vmcnt(9) conservative). vmcnt(0) only at last tile.
// LDS XOR swizzle (chunk ^= (row>>1)&3) on BOTH global_load_lds SOURCE and
// ds_read address (rule #21); SQ_LDS_BANK_CONFLICT == 0 verified.
#define BM    128
#define BN    512
#define BK    32
#define XROWS 516   // 512 t + 4 halo rows (kw window)

typedef __attribute__((ext_vector_type(8))) short   short8;
typedef __attribute__((ext_vector_type(4))) float   floatx4;

__device__ __forceinline__ unsigned short f2bf(float f) {
    unsigned int u = __builtin_bit_cast(unsigned int, f);
    u += 0x7fffu + ((u >> 16) & 1u);   // RNE
    return (unsigned short)(u >> 16);
}

__device__ __forceinline__ void gl_lds16(const void* g, void* l) {
    __builtin_amdgcn_global_load_lds(
        (const __attribute__((address_space(1))) unsigned int*)g,
        (__attribute__((address_space(3))) unsigned int*)l, 16, 0, 0);
}

// ---------------- pre-kernel 1: W fp32 [co][ci][kw] -> bf16 [kw][co][ci] ----
__global__ __launch_bounds__(256)
void wconv_kernel(const float* __restrict__ w, unsigned short* __restrict__ wbf) {
    int i = blockIdx.x * 256 + threadIdx.x;
    if (i < COUT * CIN * KW_) {
        int kw = i % KW_;
        int r  = i / KW_;
        int ci = r % CIN;
        int co = r / CIN;
        wbf[((size_t)kw * COUT + co) * CIN + ci] = f2bf(w[i]);
    }
}

// ---------------- pre-kernel 2: X fp32 [b][ci][t] -> bf16 [b][t][ci] --------
__global__ __launch_bounds__(256)
void xtrans_kernel(const float* __restrict__ x, unsigned short* __restrict__ xbf) {
    __shared__ float tile[64][68];
    const int t0  = blockIdx.x * 64;
    const int ci0 = blockIdx.y * 64;
    const int b   = blockIdx.z;
    const int tid = threadIdx.x;

    const float* xb = x + ((size_t)b * CIN + ci0) * T_IN + t0;
    const int cl = tid >> 4, fc = tid & 15;
#pragma unroll
    for (int p = 0; p < 4; ++p) {
        float4 v = *reinterpret_cast<const float4*>(xb + (size_t)(cl + p * 16) * T_IN + fc * 4);
        *reinterpret_cast<float4*>(&tile[cl + p * 16][fc * 4]) = v;
    }
    __syncthreads();

    const int tl = tid >> 2, cg = (tid & 3) * 16;
    unsigned short tmp[16];
#pragma unroll
    for (int j = 0; j < 16; ++j) tmp[j] = f2bf(tile[cg + j][tl]);
    unsigned short* dst = xbf + ((size_t)b * T_IN + t0 + tl) * CIN + ci0 + cg;
    *reinterpret_cast<short8*>(dst)     = *reinterpret_cast<short8*>(tmp);
    *reinterpret_cast<short8*>(dst + 8) = *reinterpret_cast<short8*>(tmp + 8);
}

// --- main kernel: 128x512 block, 8 waves of 128x64, dbuf + counted vmcnt ----
__global__ __launch_bounds__(512, 2)
void tdl_conv_w512(const unsigned short* __restrict__ xbf,
                   const unsigned short* __restrict__ wbf,
                   const float* __restrict__ bias,
                   float* __restrict__ out)
{
    // Wl: 2 x [5][128][32] bf16 = 81920 B ; Xl: 2 x [516][32] bf16 = 66048 B
    // total 147968 B <= 160 KiB -> 1 block/CU (8 waves, 2/SIMD)
    __shared__ __align__(16) unsigned short Wl[2][KW_ * BM * BK];
    __shared__ __align__(16) unsigned short Xl[2][XROWS * BK];

    const int tid  = threadIdx.x;
    const int lane = tid & 63;
    const int wn   = tid >> 6;   // 0..7 (t); every wave owns all 128 co rows

    // XCD-aware swizzle (grid 1024 % 8 == 0 -> bijective)
    const int bid     = blockIdx.x;
    const int logical = ((bid & 7) << 7) | (bid >> 3);
    const int co_t = logical & 3;
    const int t_t  = (logical >> 2) & 3;
    const int b    = logical >> 4;

    const int co0 = co_t * BM;
    const int t0  = t_t * BN;

    const unsigned short* xb = xbf + (size_t)b * T_IN * CIN;

    floatx4 acc[8][4];
#pragma unroll
    for (int m = 0; m < 8; ++m)
#pragma unroll
        for (int n = 0; n < 4; ++n)
            acc[m][n] = (floatx4)(0.0f);

    const int arow = lane & 15;
    const int c0   = lane >> 4;                       // logical 16B chunk
    const int aswz = ((c0 ^ ((arow >> 1) & 3)) << 3); // W read swizzle (elems)

    // ---- staging: W 2560 chunks (5/thread), X 2064 chunks (4/thread + 16 tail)
    auto stage = [&](int sel, int ci0) {
#pragma unroll
        for (int it = 0; it < 5; ++it) {
            const int e  = tid + it * 512;
            const int kw = e >> 9;
            const int r  = e & 511;
            const int co = r >> 2;
            const int c8 = (((r & 3) ^ ((co >> 1) & 3)) << 3);
            gl_lds16(wbf + ((size_t)(kw * COUT + co0 + co)) * CIN + ci0 + c8,
                     &Wl[sel][e * 8]);
        }
#pragma unroll
        for (int it = 0; it < 4; ++it) {
            const int e  = tid + it * 512;
            const int t  = e >> 2;
            const int c8 = (((e & 3) ^ ((t >> 1) & 3)) << 3);
            gl_lds16(xb + (size_t)(t0 + t) * CIN + ci0 + c8, &Xl[sel][e * 8]);
        }
        if (tid < 16) {
            const int e  = 2048 + tid;
            const int t  = e >> 2;   // 512..515
            const int c8 = (((e & 3) ^ ((t >> 1) & 3)) << 3);
            int ts = t0 + t; if (ts > T_IN - 1) ts = T_IN - 1;  // feeds masked cols only
            gl_lds16(xb + (size_t)ts * CIN + ci0 + c8, &Xl[sel][e * 8]);
        }
    };

    // compute: per kw read bfr[4] + af[8] (12 ds_read_b128) then 32 MFMAs.
    // Plain loads, no setprio, no banking (R8: both null-or-harmful here).
    auto compute = [&](int sel) {
#pragma unroll
        for (int kw = 0; kw < KW_; ++kw) {
            // X swizzle: row = wn*64+n*16+arow+kw -> (row>>1)&3 = ((arow+kw)>>1)&3
            const int bswz = ((c0 ^ (((arow + kw) >> 1) & 3)) << 3);
            short8 bfr[4], af[8];
#pragma unroll
            for (int n = 0; n < 4; ++n)
                bfr[n] = *reinterpret_cast<const short8*>(
                    &Xl[sel][(wn * 64 + n * 16 + arow + kw) * BK + bswz]);
#pragma unroll
            for (int m = 0; m < 8; ++m)
                af[m] = *reinterpret_cast<const short8*>(
                    &Wl[sel][(kw * BM + m * 16 + arow) * BK + aswz]);
#pragma unroll
            for (int m = 0; m < 8; ++m)
#pragma unroll
                for (int n = 0; n < 4; ++n)
                    acc[m][n] = __builtin_amdgcn_mfma_f32_16x16x32_bf16(
                        af[m], bfr[n], acc[m][n], 0, 0, 0);
        }
    };

    // ---- pipelined K-loop: 16 ci-tiles, 2x unrolled for static buffer sel ----
    stage(0, 0);
#pragma unroll 1
    for (int i = 0; i < 16; i += 2) {
        // even half: prefetch tile i+1 into buf1, compute tile i from buf0
        stage(1, (i + 1) * BK);
        asm volatile("s_waitcnt vmcnt(9)" ::: "memory");   // tile-i loads landed
        __builtin_amdgcn_sched_barrier(0);
        __builtin_amdgcn_s_barrier();
        __builtin_amdgcn_sched_barrier(0);
        compute(0);
        __builtin_amdgcn_s_barrier();                      // buf0 reads done
        __builtin_amdgcn_sched_barrier(0);

        // odd half: prefetch tile i+2 into buf0, compute tile i+1 from buf1
        if (i + 2 < 16) {
            stage(0, (i + 2) * BK);
            asm volatile("s_waitcnt vmcnt(9)" ::: "memory");
        } else {
            asm volatile("s_waitcnt vmcnt(0)" ::: "memory");
        }
        __builtin_amdgcn_sched_barrier(0);
        __builtin_amdgcn_s_barrier();
        __builtin_amdgcn_sched_barrier(0);
        compute(1);
        __builtin_amdgcn_s_barrier();                      // buf1 reads done
        __builtin_amdgcn_sched_barrier(0);
    }

    // ---- epilogue: D layout col = lane&15 (t), row = (lane>>4)*4 + r (co)
    const int colb = wn * 64 + (lane & 15);
    const int rowb = (lane >> 4) * 4;
    float* outp = out + ((size_t)b * COUT + co0) * TOUT + t0;
#pragma unroll
    for (int m = 0; m < 8; ++m) {
        const int row0 = rowb + m * 16;
        float bv[4];
#pragma unroll
        for (int r = 0; r < 4; ++r) bv[r] = bias[co0 + row0 + r];
#pragma unroll
        for (int n = 0; n < 4; ++n) {
            const int col = colb + n * 16;
            if (t0 + col < TOUT) {
#pragma unroll
                for (int r = 0; r < 4; ++r)
                    outp[(size_t)(row0 + r) * TOUT + col] = acc[m][n][r] + bv[r];
            }
        }
    }
}

// ---------------- fallback (round-1 kernel, used if ws too small) -----------
#define PAD   40
__global__ __launch_bounds__(256, 2)
void tdl_conv_mfma(const float* __restrict__ x,
                   const float* __restrict__ w,
                   const float* __restrict__ bias,
                   float* __restrict__ out)
{
    __shared__ __align__(16) unsigned short Wlds[KW_][BM][PAD];
    __shared__ __align__(16) unsigned short Xlds[BM + 4][PAD];

    const int tid  = threadIdx.x;
    const int lane = tid & 63;
    const int wid  = tid >> 6;
    const int wm   = wid >> 1;
    const int wn   = wid & 1;

    const int bid  = blockIdx.x;
    const int co_t = bid & 3;
    const int t_t  = (bid >> 2) & 15;
    const int b    = bid >> 6;

    const int co0 = co_t * BM;
    const int t0  = t_t * BM;

    floatx4 acc[4][4];
#pragma unroll
    for (int m = 0; m < 4; ++m)
#pragma unroll
        for (int n = 0; n < 4; ++n)
            acc[m][n] = (floatx4)(0.0f);

    const float* xb = x + (size_t)b * CIN * T_IN;
    const int arow = lane & 15;
    const int k8   = (lane >> 4) * 8;

    for (int ci0 = 0; ci0 < CIN; ci0 += BK) {
        for (int e = tid; e < BK * 33; e += 256) {
            const int ci = e / 33;
            const int q  = e - ci * 33;
            const int tt = q * 4;
            const int tg = t0 + tt;
            float4 v = make_float4(0.f, 0.f, 0.f, 0.f);
            if (tg < T_IN)
                v = *reinterpret_cast<const float4*>(xb + (size_t)(ci0 + ci) * T_IN + tg);
            Xlds[tt + 0][ci] = f2bf(v.x);
            Xlds[tt + 1][ci] = f2bf(v.y);
            Xlds[tt + 2][ci] = f2bf(v.z);
            Xlds[tt + 3][ci] = f2bf(v.w);
        }
        for (int e = tid; e < BM * 40; e += 256) {
            const int co = e / 40;
            const int q  = e - co * 40;
            const float4 v = *reinterpret_cast<const float4*>(
                w + (size_t)(co0 + co) * (CIN * KW_) + ci0 * KW_ + q * 4);
            const int m0 = q * 4;
            Wlds[(m0    ) % 5][co][(m0    ) / 5] = f2bf(v.x);
            Wlds[(m0 + 1) % 5][co][(m0 + 1) / 5] = f2bf(v.y);
            Wlds[(m0 + 2) % 5][co][(m0 + 2) / 5] = f2bf(v.z);
            Wlds[(m0 + 3) % 5][co][(m0 + 3) / 5] = f2bf(v.w);
        }
        __syncthreads();
#pragma unroll
        for (int kw = 0; kw < KW_; ++kw) {
            short8 afrag[4], bfrag[4];
#pragma unroll
            for (int m = 0; m < 4; ++m)
                afrag[m] = *reinterpret_cast<const short8*>(
                    &Wlds[kw][wm * 64 + m * 16 + arow][k8]);
#pragma unroll
            for (int n = 0; n < 4; ++n)
                bfrag[n] = *reinterpret_cast<const short8*>(
                    &Xlds[wn * 64 + n * 16 + arow + kw][k8]);
#pragma unroll
            for (int m = 0; m < 4; ++m)
#pragma unroll
                for (int n = 0; n < 4; ++n)
                    acc[m][n] = __builtin_amdgcn_mfma_f32_16x16x32_bf16(
                        afrag[m], bfrag[n], acc[m][n], 0, 0, 0);
        }
        __syncthreads();
    }

    const int colb = wn * 64 + (lane & 15);
    const int rowb = wm * 64 + (lane >> 4) * 4;
    float* outp = out + ((size_t)b * COUT + co0) * TOUT + t0;
#pragma unroll
    for (int m = 0; m < 4; ++m) {
        const int row0 = rowb + m * 16;
        float bv[4];
#pragma unroll
        for (int r = 0; r < 4; ++r) bv[r] = bias[co0 + row0 + r];
#pragma unroll
        for (int n = 0; n < 4; ++n) {
            const int col = colb + n * 16;
            if (t0 + col < TOUT) {
#pragma unroll
                for (int r = 0; r < 4; ++r)
                    outp[(size_t)(row0 + r) * TOUT + col] = acc[m][n][r] + bv[r];
            }
        }
    }
}

extern "C" void kernel_launch(void* const* d_in, const int* in_sizes, int n_in,
                              void* d_out, int out_size, void* d_ws, size_t ws_size,
                              hipStream_t stream) {
    const float* x    = (const float*)d_in[0];
    const float* w    = (const float*)d_in[1];
    const float* bias = (const float*)d_in[2];
    float* out        = (float*)d_out;

    const size_t xbf_elems = (size_t)B_SZ * T_IN * CIN;
    const size_t wbf_elems = (size_t)KW_ * COUT * CIN;
    const size_t need = (xbf_elems + wbf_elems) * sizeof(unsigned short);

    if (ws_size >= need) {
        unsigned short* xbf = (unsigned short*)d_ws;
        unsigned short* wbf = xbf + xbf_elems;

        wconv_kernel<<<(COUT * CIN * KW_ + 255) / 256, 256, 0, stream>>>(w, wbf);
        dim3 tg(T_IN / 64, CIN / 64, B_SZ);
        xtrans_kernel<<<tg, 256, 0, stream>>>(x, xbf);
        // grid: 4 co-tiles * 4 t-tiles * 64 batches = 1024 blocks, 1/CU
        tdl_conv_w512<<<4 * 4 * B_SZ, 512, 0, stream>>>(xbf, wbf, bias, out);
    } else {
        tdl_conv_mfma<<<4 * 16 * B_SZ, 256, 0, stream>>>(x, w, bias, out);
    }
}